// Round 1
// baseline (288.532 us; speedup 1.0000x reference)
//
#include <hip/hip_runtime.h>
#include <hip/hip_bf16.h>

#define D_MODEL 1024
#define NH 16
#define DK 64
#define SEQ 2048
#define BATCH 2
#define NTOK (BATCH * SEQ)   // 4096
#define SCALE 0.125f
#define EPS 1e-6f

typedef __attribute__((ext_vector_type(4))) float f32x4;
typedef __attribute__((ext_vector_type(8))) short s16x8;
typedef __hip_bfloat16 bf16;

static __device__ __forceinline__ s16x8 ld8(const bf16* p) {
    return *reinterpret_cast<const s16x8*>(p);
}

// ---------------- RMSNorm: h[4096][1024] fp32 -> hn bf16 ----------------
__global__ __launch_bounds__(256) void k_rmsnorm(const float* __restrict__ h,
                                                 const float* __restrict__ g,
                                                 bf16* __restrict__ hn) {
    const int row = blockIdx.x;
    const int tid = threadIdx.x;
    const float4 x = reinterpret_cast<const float4*>(h + (size_t)row * D_MODEL)[tid];
    float ss = x.x * x.x + x.y * x.y + x.z * x.z + x.w * x.w;
#pragma unroll
    for (int off = 32; off; off >>= 1) ss += __shfl_xor(ss, off);
    __shared__ float red[4];
    if ((tid & 63) == 0) red[tid >> 6] = ss;
    __syncthreads();
    const float tot = red[0] + red[1] + red[2] + red[3];
    const float rs = rsqrtf(tot * (1.0f / D_MODEL) + EPS);
    const float4 gg = reinterpret_cast<const float4*>(g)[tid];
    bf16* o = hn + (size_t)row * D_MODEL + tid * 4;
    o[0] = __float2bfloat16(x.x * rs * gg.x);
    o[1] = __float2bfloat16(x.y * rs * gg.y);
    o[2] = __float2bfloat16(x.z * rs * gg.z);
    o[3] = __float2bfloat16(x.w * rs * gg.w);
}

// ------------- pack wq|wk|wv fp32 [K=1024][N=1024] -> bf16 dst[3072][1024] (N-major, transposed) -------------
__global__ __launch_bounds__(256) void k_packT3(const float* __restrict__ wq,
                                                const float* __restrict__ wk,
                                                const float* __restrict__ wv,
                                                bf16* __restrict__ dst) {
    __shared__ float t[32][33];
    const int kt = blockIdx.x * 32;
    const int nt = blockIdx.y * 32;   // global n in [0,3072)
    const float* W = (blockIdx.y < 32) ? wq : (blockIdx.y < 64) ? wk : wv;
    const int nl = nt & (D_MODEL - 1);
    const int tx = threadIdx.x, ty = threadIdx.y;
#pragma unroll
    for (int i = 0; i < 4; i++)
        t[ty + 8 * i][tx] = W[(size_t)(kt + ty + 8 * i) * D_MODEL + nl + tx];
    __syncthreads();
#pragma unroll
    for (int i = 0; i < 4; i++)
        dst[(size_t)(nt + ty + 8 * i) * D_MODEL + kt + tx] = __float2bfloat16(t[tx][ty + 8 * i]);
}

__global__ __launch_bounds__(256) void k_packT1(const float* __restrict__ w,
                                                bf16* __restrict__ dst) {
    __shared__ float t[32][33];
    const int kt = blockIdx.x * 32;
    const int nt = blockIdx.y * 32;
    const int tx = threadIdx.x, ty = threadIdx.y;
#pragma unroll
    for (int i = 0; i < 4; i++)
        t[ty + 8 * i][tx] = w[(size_t)(kt + ty + 8 * i) * D_MODEL + nt + tx];
    __syncthreads();
#pragma unroll
    for (int i = 0; i < 4; i++)
        dst[(size_t)(nt + ty + 8 * i) * D_MODEL + kt + tx] = __float2bfloat16(t[tx][ty + 8 * i]);
}

// ------------- QKV GEMM: hn[4096][1024] @ WqkvT -> q/k/v bf16 [B,H,S,64] -------------
__global__ __launch_bounds__(256) void k_gemm_qkv(const bf16* __restrict__ A,
                                                  const bf16* __restrict__ Bt,
                                                  const float* __restrict__ bq,
                                                  const float* __restrict__ bk,
                                                  const float* __restrict__ bv,
                                                  bf16* __restrict__ qb,
                                                  bf16* __restrict__ kb,
                                                  bf16* __restrict__ vb) {
    __shared__ bf16 As[64][40];
    __shared__ bf16 Bs[64][40];
    const int tid = threadIdx.x;
    const int w = tid >> 6, lane = tid & 63, l16 = lane & 15, lq = lane >> 4;
    const int row0 = blockIdx.y * 64, col0 = blockIdx.x * 64;
    f32x4 acc[4] = {{0,0,0,0},{0,0,0,0},{0,0,0,0},{0,0,0,0}};
    const int sr = tid >> 2, sc = (tid & 3) * 8;
    for (int kt = 0; kt < D_MODEL; kt += 32) {
        *reinterpret_cast<s16x8*>(&As[sr][sc]) = ld8(&A[(size_t)(row0 + sr) * D_MODEL + kt + sc]);
        *reinterpret_cast<s16x8*>(&Bs[sr][sc]) = ld8(&Bt[(size_t)(col0 + sr) * D_MODEL + kt + sc]);
        __syncthreads();
        const s16x8 af = ld8(&As[w * 16 + l16][lq * 8]);
#pragma unroll
        for (int nb = 0; nb < 4; nb++) {
            const s16x8 bfr = ld8(&Bs[nb * 16 + l16][lq * 8]);
            acc[nb] = __builtin_amdgcn_mfma_f32_16x16x32_bf16(af, bfr, acc[nb], 0, 0, 0);
        }
        __syncthreads();
    }
    const int which = col0 >> 10;                // 0=q 1=k 2=v
    const int cmod = col0 & (D_MODEL - 1);       // multiple of 64
    const int head = cmod >> 6;
    bf16* dst = (which == 0) ? qb : (which == 1) ? kb : vb;
    const float* bias = (which == 0) ? bq : (which == 1) ? bk : bv;
#pragma unroll
    for (int nb = 0; nb < 4; nb++) {
        const int d = nb * 16 + l16;
        const float bs = bias[cmod + d];
#pragma unroll
        for (int r = 0; r < 4; r++) {
            const int row = row0 + w * 16 + lq * 4 + r;
            const int b_ = row >> 11, s_ = row & (SEQ - 1);
            dst[(((size_t)(b_ * NH + head) * SEQ + s_) << 6) + d] =
                __float2bfloat16(acc[nb][r] + bs);
        }
    }
}

// ------------- RoPE in-place on q,k: [B*H, S, 64] bf16 -------------
__global__ __launch_bounds__(256) void k_rope(bf16* __restrict__ q, bf16* __restrict__ k) {
    const int idx = blockIdx.x * 256 + threadIdx.x;   // 2^22 threads
    const int j = idx & 31;
    const int s = (idx >> 5) & (SEQ - 1);
    const int bh = (idx >> 16) & 31;
    bf16* base = (idx >> 21) ? k : q;
    bf16* p = base + (((size_t)bh * SEQ + s) << 6);
    const float x1 = __bfloat162float(p[j]);
    const float x2 = __bfloat162float(p[j + 32]);
    const float theta = expf(-(float)j * 0.28782313662425572f);  // ln(10000)/32
    const float ang = (float)s * theta;
    float sn, cs;
    sincosf(ang, &sn, &cs);
    p[j]      = __float2bfloat16(x1 * cs - x2 * sn);
    p[j + 32] = __float2bfloat16(x2 * cs + x1 * sn);
}

// ------------- causal flash attention: q,k,v [B*H][S][64] bf16 -> ao [B,S,H,64] bf16 -------------
__global__ __launch_bounds__(256) void k_attn(const bf16* __restrict__ q,
                                              const bf16* __restrict__ kk,
                                              const bf16* __restrict__ v,
                                              bf16* __restrict__ ao) {
    __shared__ bf16 Ks[64][72];       // [n][d]
    __shared__ bf16 Vt[64][72];       // [d][n]
    __shared__ bf16 Ps[4][16][72];    // per-wave P [qrow][n]
    const int tid = threadIdx.x;
    const int w = tid >> 6, lane = tid & 63, l16 = lane & 15, lq = lane >> 4;
    const int qt = blockIdx.x, bh = blockIdx.y;
    const int qbase = qt * 64;
    const bf16* qp = q + (((size_t)bh * SEQ + qbase + w * 16 + l16) << 6);
    s16x8 qf[2];
    qf[0] = ld8(qp + lq * 8);
    qf[1] = ld8(qp + 32 + lq * 8);
    f32x4 oacc[4] = {{0,0,0,0},{0,0,0,0},{0,0,0,0},{0,0,0,0}};
    float m_[4], l_[4];
#pragma unroll
    for (int r = 0; r < 4; r++) { m_[r] = -1e30f; l_[r] = 0.0f; }
    const int sr = tid >> 2, sc = (tid & 3) * 16;
    for (int kt = 0; kt <= qt; kt++) {
        const int kb = kt * 64;
        const bf16* krow = kk + (((size_t)bh * SEQ + kb + sr) << 6) + sc;
        *reinterpret_cast<s16x8*>(&Ks[sr][sc])     = ld8(krow);
        *reinterpret_cast<s16x8*>(&Ks[sr][sc + 8]) = ld8(krow + 8);
        const bf16* vrow = v + (((size_t)bh * SEQ + kb + sr) << 6) + sc;
#pragma unroll
        for (int i = 0; i < 16; i++) Vt[sc + i][sr] = vrow[i];
        __syncthreads();
        // scores S = Q K^T
        f32x4 sacc[4] = {{0,0,0,0},{0,0,0,0},{0,0,0,0},{0,0,0,0}};
#pragma unroll
        for (int nb = 0; nb < 4; nb++) {
#pragma unroll
            for (int ks = 0; ks < 2; ks++) {
                const s16x8 kf = ld8(&Ks[nb * 16 + l16][ks * 32 + lq * 8]);
                sacc[nb] = __builtin_amdgcn_mfma_f32_16x16x32_bf16(qf[ks], kf, sacc[nb], 0, 0, 0);
            }
        }
        // online softmax (rows = lq*4+r, cols = nb*16+l16)
        float sv[4][4];
#pragma unroll
        for (int r = 0; r < 4; r++) {
            const int irow = qbase + w * 16 + lq * 4 + r;
            float mx = -1e30f;
#pragma unroll
            for (int nb = 0; nb < 4; nb++) {
                const int jcol = kb + nb * 16 + l16;
                float x = sacc[nb][r] * SCALE;
                if (jcol > irow) x = -1e30f;
                sv[r][nb] = x;
                mx = fmaxf(mx, x);
            }
#pragma unroll
            for (int off = 1; off < 16; off <<= 1) mx = fmaxf(mx, __shfl_xor(mx, off));
            const float mn = fmaxf(m_[r], mx);
            const float alpha = expf(m_[r] - mn);
            float rsum = 0.0f;
#pragma unroll
            for (int nb = 0; nb < 4; nb++) {
                const float p = expf(sv[r][nb] - mn);
                rsum += p;
                Ps[w][lq * 4 + r][nb * 16 + l16] = __float2bfloat16(p);
            }
#pragma unroll
            for (int off = 1; off < 16; off <<= 1) rsum += __shfl_xor(rsum, off);
            l_[r] = l_[r] * alpha + rsum;
            m_[r] = mn;
#pragma unroll
            for (int nb = 0; nb < 4; nb++) oacc[nb][r] *= alpha;
        }
        __syncthreads();
        // O += P V
#pragma unroll
        for (int ks = 0; ks < 2; ks++) {
            const s16x8 pa = ld8(&Ps[w][l16][ks * 32 + lq * 8]);
#pragma unroll
            for (int nb = 0; nb < 4; nb++) {
                const s16x8 vf = ld8(&Vt[nb * 16 + l16][ks * 32 + lq * 8]);
                oacc[nb] = __builtin_amdgcn_mfma_f32_16x16x32_bf16(pa, vf, oacc[nb], 0, 0, 0);
            }
        }
        __syncthreads();
    }
    const int b_ = bh >> 4, h_ = bh & (NH - 1);
#pragma unroll
    for (int r = 0; r < 4; r++) {
        const float inv = 1.0f / l_[r];
        const int srow = qbase + w * 16 + lq * 4 + r;
        bf16* orow = ao + (((size_t)(b_ * SEQ + srow) * NH + h_) << 6);
#pragma unroll
        for (int nb = 0; nb < 4; nb++)
            orow[nb * 16 + l16] = __float2bfloat16(oacc[nb][r] * inv);
    }
}

// ------------- O-proj GEMM + bias + residual: ao[4096][1024] @ woT + bo + h -> out fp32 -------------
__global__ __launch_bounds__(256) void k_gemm_out(const bf16* __restrict__ A,
                                                  const bf16* __restrict__ Bt,
                                                  const float* __restrict__ bo,
                                                  const float* __restrict__ hres,
                                                  float* __restrict__ out) {
    __shared__ bf16 As[64][40];
    __shared__ bf16 Bs[64][40];
    const int tid = threadIdx.x;
    const int w = tid >> 6, lane = tid & 63, l16 = lane & 15, lq = lane >> 4;
    const int row0 = blockIdx.y * 64, col0 = blockIdx.x * 64;
    f32x4 acc[4] = {{0,0,0,0},{0,0,0,0},{0,0,0,0},{0,0,0,0}};
    const int sr = tid >> 2, sc = (tid & 3) * 8;
    for (int kt = 0; kt < D_MODEL; kt += 32) {
        *reinterpret_cast<s16x8*>(&As[sr][sc]) = ld8(&A[(size_t)(row0 + sr) * D_MODEL + kt + sc]);
        *reinterpret_cast<s16x8*>(&Bs[sr][sc]) = ld8(&Bt[(size_t)(col0 + sr) * D_MODEL + kt + sc]);
        __syncthreads();
        const s16x8 af = ld8(&As[w * 16 + l16][lq * 8]);
#pragma unroll
        for (int nb = 0; nb < 4; nb++) {
            const s16x8 bfr = ld8(&Bs[nb * 16 + l16][lq * 8]);
            acc[nb] = __builtin_amdgcn_mfma_f32_16x16x32_bf16(af, bfr, acc[nb], 0, 0, 0);
        }
        __syncthreads();
    }
#pragma unroll
    for (int nb = 0; nb < 4; nb++) {
        const int col = col0 + nb * 16 + l16;
        const float bs = bo[col];
#pragma unroll
        for (int r = 0; r < 4; r++) {
            const int row = row0 + w * 16 + lq * 4 + r;
            out[(size_t)row * D_MODEL + col] =
                acc[nb][r] + bs + hres[(size_t)row * D_MODEL + col];
        }
    }
}

extern "C" void kernel_launch(void* const* d_in, const int* in_sizes, int n_in,
                              void* d_out, int out_size, void* d_ws, size_t ws_size,
                              hipStream_t stream) {
    (void)in_sizes; (void)n_in; (void)out_size; (void)ws_size;
    const float* h  = (const float*)d_in[0];
    const float* wq = (const float*)d_in[1];
    const float* bq = (const float*)d_in[2];
    const float* wk = (const float*)d_in[3];
    const float* bk = (const float*)d_in[4];
    const float* wv = (const float*)d_in[5];
    const float* bv = (const float*)d_in[6];
    const float* wo = (const float*)d_in[7];
    const float* bo = (const float*)d_in[8];
    const float* g  = (const float*)d_in[9];
    float* out = (float*)d_out;

    char* ws = (char*)d_ws;
    size_t off = 0;
    auto carve = [&](size_t bytes) {
        void* p = ws + off;
        off += (bytes + 255) & ~(size_t)255;
        return p;
    };
    bf16* hn    = (bf16*)carve((size_t)NTOK * D_MODEL * 2);
    bf16* wqkvT = (bf16*)carve((size_t)3 * D_MODEL * D_MODEL * 2);
    bf16* woT   = (bf16*)carve((size_t)D_MODEL * D_MODEL * 2);
    bf16* qb    = (bf16*)carve((size_t)BATCH * NH * SEQ * DK * 2);
    bf16* kb    = (bf16*)carve((size_t)BATCH * NH * SEQ * DK * 2);
    bf16* vb    = (bf16*)carve((size_t)BATCH * NH * SEQ * DK * 2);
    bf16* ao    = (bf16*)carve((size_t)NTOK * D_MODEL * 2);

    k_rmsnorm<<<NTOK, 256, 0, stream>>>(h, g, hn);
    k_packT3<<<dim3(32, 96), dim3(32, 8), 0, stream>>>(wq, wk, wv, wqkvT);
    k_packT1<<<dim3(32, 32), dim3(32, 8), 0, stream>>>(wo, woT);
    k_gemm_qkv<<<dim3(48, 64), 256, 0, stream>>>(hn, wqkvT, bq, bk, bv, qb, kb, vb);
    k_rope<<<(BATCH * NH * SEQ * 32 * 2) / 256, 256, 0, stream>>>(qb, kb);
    k_attn<<<dim3(SEQ / 64, BATCH * NH), 256, 0, stream>>>(qb, kb, vb, ao);
    k_gemm_out<<<dim3(16, 64), 256, 0, stream>>>(ao, woT, bo, h, out);
}

// Round 2
// 202.018 us; speedup vs baseline: 1.4282x; 1.4282x over previous
//
#include <hip/hip_runtime.h>
#include <hip/hip_bf16.h>

#define D_MODEL 1024
#define NH 16
#define DK 64
#define SEQ 2048
#define BATCH 2
#define NTOK (BATCH * SEQ)   // 4096
#define EPS 1e-6f

typedef __attribute__((ext_vector_type(4))) float f32x4;
typedef __attribute__((ext_vector_type(16))) float f32x16;
typedef __attribute__((ext_vector_type(8))) short s16x8;
typedef unsigned int u32;
typedef __hip_bfloat16 bf16;

static __device__ __forceinline__ s16x8 ld8(const bf16* p) {
    return *reinterpret_cast<const s16x8*>(p);
}

static __device__ __forceinline__ u32 cvtpk(float lo, float hi) {
    u32 r;
    asm volatile("v_cvt_pk_bf16_f32 %0, %1, %2" : "=v"(r) : "v"(lo), "v"(hi));
    return r;
}
// v_permlane32_swap_b32 a, b: a[32..63] <-> b[0..31]
static __device__ __forceinline__ void swap32(u32& a, u32& b) {
    asm volatile("v_permlane32_swap_b32 %0, %1" : "+v"(a), "+v"(b));
}

union W4 { s16x8 v; u32 w[4]; };

// ---------------- RMSNorm: h[4096][1024] fp32 -> hn bf16 ----------------
__global__ __launch_bounds__(256) void k_rmsnorm(const float* __restrict__ h,
                                                 const float* __restrict__ g,
                                                 bf16* __restrict__ hn) {
    const int row = blockIdx.x;
    const int tid = threadIdx.x;
    const float4 x = reinterpret_cast<const float4*>(h + (size_t)row * D_MODEL)[tid];
    float ss = x.x * x.x + x.y * x.y + x.z * x.z + x.w * x.w;
#pragma unroll
    for (int off = 32; off; off >>= 1) ss += __shfl_xor(ss, off);
    __shared__ float red[4];
    if ((tid & 63) == 0) red[tid >> 6] = ss;
    __syncthreads();
    const float tot = red[0] + red[1] + red[2] + red[3];
    const float rs = rsqrtf(tot * (1.0f / D_MODEL) + EPS);
    const float4 gg = reinterpret_cast<const float4*>(g)[tid];
    bf16* o = hn + (size_t)row * D_MODEL + tid * 4;
    o[0] = __float2bfloat16(x.x * rs * gg.x);
    o[1] = __float2bfloat16(x.y * rs * gg.y);
    o[2] = __float2bfloat16(x.z * rs * gg.z);
    o[3] = __float2bfloat16(x.w * rs * gg.w);
}

// ------------- pack wq|wk|wv fp32 [K=1024][N=1024] -> bf16 dst[3072][1024] (N-major, transposed) -------------
__global__ __launch_bounds__(256) void k_packT3(const float* __restrict__ wq,
                                                const float* __restrict__ wk,
                                                const float* __restrict__ wv,
                                                bf16* __restrict__ dst) {
    __shared__ float t[32][33];
    const int kt = blockIdx.x * 32;
    const int nt = blockIdx.y * 32;   // global n in [0,3072)
    const float* W = (blockIdx.y < 32) ? wq : (blockIdx.y < 64) ? wk : wv;
    const int nl = nt & (D_MODEL - 1);
    const int tx = threadIdx.x, ty = threadIdx.y;
#pragma unroll
    for (int i = 0; i < 4; i++)
        t[ty + 8 * i][tx] = W[(size_t)(kt + ty + 8 * i) * D_MODEL + nl + tx];
    __syncthreads();
#pragma unroll
    for (int i = 0; i < 4; i++)
        dst[(size_t)(nt + ty + 8 * i) * D_MODEL + kt + tx] = __float2bfloat16(t[tx][ty + 8 * i]);
}

__global__ __launch_bounds__(256) void k_packT1(const float* __restrict__ w,
                                                bf16* __restrict__ dst) {
    __shared__ float t[32][33];
    const int kt = blockIdx.x * 32;
    const int nt = blockIdx.y * 32;
    const int tx = threadIdx.x, ty = threadIdx.y;
#pragma unroll
    for (int i = 0; i < 4; i++)
        t[ty + 8 * i][tx] = w[(size_t)(kt + ty + 8 * i) * D_MODEL + nt + tx];
    __syncthreads();
#pragma unroll
    for (int i = 0; i < 4; i++)
        dst[(size_t)(nt + ty + 8 * i) * D_MODEL + kt + tx] = __float2bfloat16(t[tx][ty + 8 * i]);
}

// ------------- QKV GEMM: hn[4096][1024] @ WqkvT -> q/k/v bf16 [B,H,S,64] -------------
__global__ __launch_bounds__(256) void k_gemm_qkv(const bf16* __restrict__ A,
                                                  const bf16* __restrict__ Bt,
                                                  const float* __restrict__ bq,
                                                  const float* __restrict__ bk,
                                                  const float* __restrict__ bv,
                                                  bf16* __restrict__ qb,
                                                  bf16* __restrict__ kb,
                                                  bf16* __restrict__ vb) {
    __shared__ bf16 As[64][40];
    __shared__ bf16 Bs[64][40];
    const int tid = threadIdx.x;
    const int w = tid >> 6, lane = tid & 63, l16 = lane & 15, lq = lane >> 4;
    const int row0 = blockIdx.y * 64, col0 = blockIdx.x * 64;
    f32x4 acc[4] = {{0,0,0,0},{0,0,0,0},{0,0,0,0},{0,0,0,0}};
    const int sr = tid >> 2, sc = (tid & 3) * 8;
    for (int kt = 0; kt < D_MODEL; kt += 32) {
        *reinterpret_cast<s16x8*>(&As[sr][sc]) = ld8(&A[(size_t)(row0 + sr) * D_MODEL + kt + sc]);
        *reinterpret_cast<s16x8*>(&Bs[sr][sc]) = ld8(&Bt[(size_t)(col0 + sr) * D_MODEL + kt + sc]);
        __syncthreads();
        const s16x8 af = ld8(&As[w * 16 + l16][lq * 8]);
#pragma unroll
        for (int nb = 0; nb < 4; nb++) {
            const s16x8 bfr = ld8(&Bs[nb * 16 + l16][lq * 8]);
            acc[nb] = __builtin_amdgcn_mfma_f32_16x16x32_bf16(af, bfr, acc[nb], 0, 0, 0);
        }
        __syncthreads();
    }
    const int which = col0 >> 10;                // 0=q 1=k 2=v
    const int cmod = col0 & (D_MODEL - 1);       // multiple of 64
    const int head = cmod >> 6;
    bf16* dst = (which == 0) ? qb : (which == 1) ? kb : vb;
    const float* bias = (which == 0) ? bq : (which == 1) ? bk : bv;
#pragma unroll
    for (int nb = 0; nb < 4; nb++) {
        const int d = nb * 16 + l16;
        const float bs = bias[cmod + d];
#pragma unroll
        for (int r = 0; r < 4; r++) {
            const int row = row0 + w * 16 + lq * 4 + r;
            const int b_ = row >> 11, s_ = row & (SEQ - 1);
            dst[(((size_t)(b_ * NH + head) * SEQ + s_) << 6) + d] =
                __float2bfloat16(acc[nb][r] + bs);
        }
    }
}

// ------------- RoPE in-place on q,k: [B*H, S, 64] bf16; q additionally pre-scaled by 0.125 -------------
__global__ __launch_bounds__(256) void k_rope(bf16* __restrict__ q, bf16* __restrict__ k) {
    const int idx = blockIdx.x * 256 + threadIdx.x;   // 2^22 threads
    const int j = idx & 31;
    const int s = (idx >> 5) & (SEQ - 1);
    const int bh = (idx >> 16) & 31;
    const int isk = idx >> 21;
    bf16* base = isk ? k : q;
    const float osc = isk ? 1.0f : 0.125f;            // fold softmax scale into q (exact pow2)
    bf16* p = base + (((size_t)bh * SEQ + s) << 6);
    const float x1 = __bfloat162float(p[j]);
    const float x2 = __bfloat162float(p[j + 32]);
    const float theta = expf(-(float)j * 0.28782313662425572f);  // ln(10000)/32
    const float ang = (float)s * theta;
    float sn, cs;
    sincosf(ang, &sn, &cs);
    p[j]      = __float2bfloat16((x1 * cs - x2 * sn) * osc);
    p[j + 32] = __float2bfloat16((x2 * cs + x1 * sn) * osc);
}

// ------------- V transpose: vb[bh][s][64] -> vt[bh][64][s] -------------
__global__ __launch_bounds__(256) void k_transpose_v(const bf16* __restrict__ vb,
                                                     bf16* __restrict__ vt) {
    __shared__ short t[64][72];
    const int bh = blockIdx.y;
    const int s0 = blockIdx.x << 6;
    const int tid = threadIdx.x;
    const int r = tid >> 2, c0 = (tid & 3) << 4;
    const bf16* src = vb + (((size_t)bh * SEQ + s0 + r) << 6) + c0;
    *reinterpret_cast<s16x8*>(&t[r][c0]) = ld8(src);
    *reinterpret_cast<s16x8*>(&t[r][c0 + 8]) = ld8(src + 8);
    __syncthreads();
    s16x8 a, b;
#pragma unroll
    for (int i = 0; i < 8; i++) a[i] = t[c0 + i][r];
#pragma unroll
    for (int i = 0; i < 8; i++) b[i] = t[c0 + 8 + i][r];
    bf16* dst = vt + (size_t)(bh * 64 + r) * SEQ + s0 + c0;
    *reinterpret_cast<s16x8*>(dst) = a;
    *reinterpret_cast<s16x8*>(dst + 8) = b;
}

// ------------- causal flash attention, LDS-free, swapped QK^T -------------
// q (pre-scaled), k: [bh][S][64]; vt: [bh][64][S]; out ao: [B,S,H*64] bf16
__global__ void k_attn2(const bf16* __restrict__ qg,
                        const bf16* __restrict__ kg,
                        const bf16* __restrict__ vt,
                        bf16* __restrict__ ao) {
    const int tid = threadIdx.x;
    const int w = tid >> 6;
    const int lane = tid & 63;
    const int l31 = lane & 31;
    const int hi = lane >> 5;
    const int bh = blockIdx.y;
    const int blk = blockIdx.x;   // 0..15
    // balanced wave->q-position map: {i, 31-i, 32+i, 63-i} sums constant
    int pos;
    switch (w) {
        case 0:  pos = blk;      break;
        case 1:  pos = 31 - blk; break;
        case 2:  pos = 32 + blk; break;
        default: pos = 63 - blk; break;
    }
    const int qw = pos << 5;           // first q row of this wave
    const int qrow = qw + l31;         // this lane's q row (C col = lane&31)

    // Q B-fragments: lane holds Q[qrow][16t + 8*hi + e], e=0..7
    const bf16* qptr = qg + (((size_t)bh * SEQ + qrow) << 6) + 8 * hi;
    s16x8 qf[4];
#pragma unroll
    for (int t = 0; t < 4; t++) qf[t] = ld8(qptr + 16 * t);

    f32x16 o0, o1;                     // O^T accum: d-blocks 0/1, col=q
#pragma unroll
    for (int r = 0; r < 16; r++) { o0[r] = 0.0f; o1[r] = 0.0f; }
    float m_run = -1e30f, l_run = 0.0f;

    const int nfull = qw >> 6;         // fully-unmasked K-tiles
    const int ntot  = (qw + 95) >> 6;  // total K-tiles for this wave
    const bf16* kbase = kg + (((size_t)bh * SEQ) << 6);
    const bf16* vbase = vt + (size_t)bh * 64 * SEQ;

    for (int kt = 0; kt < ntot; kt++) {
        const int kb = kt << 6;
        // S^T = K · Q^T (two 32-row j-blocks, K=16 steps over d)
        f32x16 s0, s1;
#pragma unroll
        for (int r = 0; r < 16; r++) { s0[r] = 0.0f; s1[r] = 0.0f; }
#pragma unroll
        for (int t = 0; t < 4; t++) {
            const s16x8 kf0 = ld8(kbase + ((size_t)(kb + l31) << 6) + 16 * t + 8 * hi);
            const s16x8 kf1 = ld8(kbase + ((size_t)(kb + 32 + l31) << 6) + 16 * t + 8 * hi);
            s0 = __builtin_amdgcn_mfma_f32_32x32x16_bf16(kf0, qf[t], s0, 0, 0, 0);
            s1 = __builtin_amdgcn_mfma_f32_32x32x16_bf16(kf1, qf[t], s1, 0, 0, 0);
        }
        float p[32];
#pragma unroll
        for (int r = 0; r < 16; r++) { p[r] = s0[r]; p[16 + r] = s1[r]; }
        if (kt >= nfull) {             // diagonal tile: causal mask (wave-uniform branch)
#pragma unroll
            for (int r = 0; r < 32; r++) {
                const int j = kb + 8 * (r >> 2) + (r & 3) + 4 * hi;
                if (j > qrow) p[r] = -3.0e38f;
            }
        }
        // online softmax: in-lane 31-op max + one cross-half shuffle
        float mx = p[0];
#pragma unroll
        for (int r = 1; r < 32; r++) mx = fmaxf(mx, p[r]);
        mx = fmaxf(mx, __shfl_xor(mx, 32));
        if (!__all(mx <= m_run + 8.0f)) {   // defer-max (T13)
            const float mn = fmaxf(m_run, mx);
            const float alpha = __expf(m_run - mn);
            m_run = mn;
            l_run *= alpha;
#pragma unroll
            for (int r = 0; r < 16; r++) { o0[r] *= alpha; o1[r] *= alpha; }
        }
        float rs = 0.0f;
#pragma unroll
        for (int r = 0; r < 32; r++) { p[r] = __expf(p[r] - m_run); rs += p[r]; }
        rs += __shfl_xor(rs, 32);
        l_run += rs;
        // P^T -> PV B-fragments: cvt_pk pairs + permlane32_swap half-exchange (T12)
        u32 pk_[16];
#pragma unroll
        for (int a = 0; a < 8; a++) {
            pk_[2 * a]     = cvtpk(p[4 * a],     p[4 * a + 1]);
            pk_[2 * a + 1] = cvtpk(p[4 * a + 2], p[4 * a + 3]);
        }
#pragma unroll
        for (int m = 0; m < 4; m++) {
            u32 b0 = pk_[4 * m],     b2 = pk_[4 * m + 2];
            u32 b1 = pk_[4 * m + 1], b3 = pk_[4 * m + 3];
            swap32(b0, b2);
            swap32(b1, b3);
            W4 B; B.w[0] = b0; B.w[1] = b1; B.w[2] = b2; B.w[3] = b3;
            const bf16* vrow = vbase + (size_t)l31 * SEQ + kb + 16 * m + 8 * hi;
            const s16x8 v0 = ld8(vrow);
            const s16x8 v1 = ld8(vrow + (size_t)32 * SEQ);
            o0 = __builtin_amdgcn_mfma_f32_32x32x16_bf16(v0, B.v, o0, 0, 0, 0);
            o1 = __builtin_amdgcn_mfma_f32_32x32x16_bf16(v1, B.v, o1, 0, 0, 0);
        }
    }
    // epilogue: normalize, pack, 8B stores. o? reg r -> d = (db*32) + 8*(r>>2) + (r&3) + 4*hi
    const float inv = 1.0f / l_run;
    const int b_ = bh >> 4, h_ = bh & (NH - 1);
    bf16* orow = ao + (((size_t)(b_ * SEQ + qrow)) << 10) + (h_ << 6);
#pragma unroll
    for (int g = 0; g < 4; g++) {
        {
            uint2 val;
            val.x = cvtpk(o0[4 * g] * inv, o0[4 * g + 1] * inv);
            val.y = cvtpk(o0[4 * g + 2] * inv, o0[4 * g + 3] * inv);
            *reinterpret_cast<uint2*>(orow + 8 * g + 4 * hi) = val;
        }
        {
            uint2 val;
            val.x = cvtpk(o1[4 * g] * inv, o1[4 * g + 1] * inv);
            val.y = cvtpk(o1[4 * g + 2] * inv, o1[4 * g + 3] * inv);
            *reinterpret_cast<uint2*>(orow + 32 + 8 * g + 4 * hi) = val;
        }
    }
}

// ------------- O-proj GEMM + bias + residual: ao[4096][1024] @ woT + bo + h -> out fp32 -------------
__global__ __launch_bounds__(256) void k_gemm_out(const bf16* __restrict__ A,
                                                  const bf16* __restrict__ Bt,
                                                  const float* __restrict__ bo,
                                                  const float* __restrict__ hres,
                                                  float* __restrict__ out) {
    __shared__ bf16 As[64][40];
    __shared__ bf16 Bs[64][40];
    const int tid = threadIdx.x;
    const int w = tid >> 6, lane = tid & 63, l16 = lane & 15, lq = lane >> 4;
    const int row0 = blockIdx.y * 64, col0 = blockIdx.x * 64;
    f32x4 acc[4] = {{0,0,0,0},{0,0,0,0},{0,0,0,0},{0,0,0,0}};
    const int sr = tid >> 2, sc = (tid & 3) * 8;
    for (int kt = 0; kt < D_MODEL; kt += 32) {
        *reinterpret_cast<s16x8*>(&As[sr][sc]) = ld8(&A[(size_t)(row0 + sr) * D_MODEL + kt + sc]);
        *reinterpret_cast<s16x8*>(&Bs[sr][sc]) = ld8(&Bt[(size_t)(col0 + sr) * D_MODEL + kt + sc]);
        __syncthreads();
        const s16x8 af = ld8(&As[w * 16 + l16][lq * 8]);
#pragma unroll
        for (int nb = 0; nb < 4; nb++) {
            const s16x8 bfr = ld8(&Bs[nb * 16 + l16][lq * 8]);
            acc[nb] = __builtin_amdgcn_mfma_f32_16x16x32_bf16(af, bfr, acc[nb], 0, 0, 0);
        }
        __syncthreads();
    }
#pragma unroll
    for (int nb = 0; nb < 4; nb++) {
        const int col = col0 + nb * 16 + l16;
        const float bs = bo[col];
#pragma unroll
        for (int r = 0; r < 4; r++) {
            const int row = row0 + w * 16 + lq * 4 + r;
            out[(size_t)row * D_MODEL + col] =
                acc[nb][r] + bs + hres[(size_t)row * D_MODEL + col];
        }
    }
}

extern "C" void kernel_launch(void* const* d_in, const int* in_sizes, int n_in,
                              void* d_out, int out_size, void* d_ws, size_t ws_size,
                              hipStream_t stream) {
    (void)in_sizes; (void)n_in; (void)out_size; (void)ws_size;
    const float* h  = (const float*)d_in[0];
    const float* wq = (const float*)d_in[1];
    const float* bq = (const float*)d_in[2];
    const float* wk = (const float*)d_in[3];
    const float* bk = (const float*)d_in[4];
    const float* wv = (const float*)d_in[5];
    const float* bv = (const float*)d_in[6];
    const float* wo = (const float*)d_in[7];
    const float* bo = (const float*)d_in[8];
    const float* g  = (const float*)d_in[9];
    float* out = (float*)d_out;

    char* ws = (char*)d_ws;
    size_t off = 0;
    auto carve = [&](size_t bytes) {
        void* p = ws + off;
        off += (bytes + 255) & ~(size_t)255;
        return p;
    };
    bf16* hn    = (bf16*)carve((size_t)NTOK * D_MODEL * 2);
    bf16* wqkvT = (bf16*)carve((size_t)3 * D_MODEL * D_MODEL * 2);
    bf16* woT   = (bf16*)carve((size_t)D_MODEL * D_MODEL * 2);
    bf16* qb    = (bf16*)carve((size_t)BATCH * NH * SEQ * DK * 2);
    bf16* kb    = (bf16*)carve((size_t)BATCH * NH * SEQ * DK * 2);
    bf16* vb    = (bf16*)carve((size_t)BATCH * NH * SEQ * DK * 2);
    bf16* ao    = (bf16*)carve((size_t)NTOK * D_MODEL * 2);
    bf16* vtr   = hn;   // alias: hn is dead after k_gemm_qkv; vt fits exactly (8MB)

    k_rmsnorm<<<NTOK, 256, 0, stream>>>(h, g, hn);
    k_packT3<<<dim3(32, 96), dim3(32, 8), 0, stream>>>(wq, wk, wv, wqkvT);
    k_packT1<<<dim3(32, 32), dim3(32, 8), 0, stream>>>(wo, woT);
    k_gemm_qkv<<<dim3(48, 64), 256, 0, stream>>>(hn, wqkvT, bq, bk, bv, qb, kb, vb);
    k_rope<<<(BATCH * NH * SEQ * 32 * 2) / 256, 256, 0, stream>>>(qb, kb);
    k_transpose_v<<<dim3(SEQ / 64, BATCH * NH), 256, 0, stream>>>(vb, vtr);
    k_attn2<<<dim3(16, BATCH * NH), 256, 0, stream>>>(qb, kb, vtr, ao);
    k_gemm_out<<<dim3(16, 64), 256, 0, stream>>>(ao, woT, bo, h, out);
}

// Round 4
// 182.357 us; speedup vs baseline: 1.5822x; 1.1078x over previous
//
#include <hip/hip_runtime.h>
#include <hip/hip_bf16.h>

#define D_MODEL 1024
#define NH 16
#define DK 64
#define SEQ 2048
#define BATCH 2
#define NTOK (BATCH * SEQ)   // 4096
#define EPS 1e-6f

typedef __attribute__((ext_vector_type(4))) float f32x4;
typedef __attribute__((ext_vector_type(16))) float f32x16;
typedef __attribute__((ext_vector_type(8))) short s16x8;
typedef unsigned int u32;
typedef __hip_bfloat16 bf16;

#define AS1 __attribute__((address_space(1)))
#define AS3 __attribute__((address_space(3)))

static __device__ __forceinline__ s16x8 ld8(const bf16* p) {
    return *reinterpret_cast<const s16x8*>(p);
}
// bf16 bits (in a short) -> float, no address-of
static __device__ __forceinline__ float b2f(short s) {
    return __uint_as_float(((u32)(unsigned short)s) << 16);
}

static __device__ __forceinline__ u32 cvtpk(float lo, float hi) {
    u32 r;
    asm volatile("v_cvt_pk_bf16_f32 %0, %1, %2" : "=v"(r) : "v"(lo), "v"(hi));
    return r;
}
static __device__ __forceinline__ void swap32(u32& a, u32& b) {
    asm volatile("v_permlane32_swap_b32 %0, %1" : "+v"(a), "+v"(b));
}
// async global->LDS, 16B per lane; lds dest must be wave-uniform base (HW adds lane*16)
static __device__ __forceinline__ void gld_lds16(const bf16* g, bf16* l) {
    __builtin_amdgcn_global_load_lds((const AS1 void*)g, (AS3 void*)l, 16, 0, 0);
}

union W4 { s16x8 v; u32 w[4]; };

// ---------------- cos/sin table: tab[s][i] for s<2048, i<32 ----------------
__global__ __launch_bounds__(256) void k_tab(float2* __restrict__ tab) {
    const int idx = blockIdx.x * 256 + threadIdx.x;   // 65536
    const int s = idx >> 5, i = idx & 31;
    const float theta = __expf(-(float)i * 0.28782313662425572f);  // ln(10000)/32
    float sn, cs;
    sincosf((float)s * theta, &sn, &cs);
    tab[idx] = make_float2(cs, sn);
}

// ---------------- RMSNorm: h[4096][1024] fp32 -> hn bf16 ----------------
__global__ __launch_bounds__(256) void k_rmsnorm(const float* __restrict__ h,
                                                 const float* __restrict__ g,
                                                 bf16* __restrict__ hn) {
    const int row = blockIdx.x;
    const int tid = threadIdx.x;
    const float4 x = reinterpret_cast<const float4*>(h + (size_t)row * D_MODEL)[tid];
    float ss = x.x * x.x + x.y * x.y + x.z * x.z + x.w * x.w;
#pragma unroll
    for (int off = 32; off; off >>= 1) ss += __shfl_xor(ss, off);
    __shared__ float red[4];
    if ((tid & 63) == 0) red[tid >> 6] = ss;
    __syncthreads();
    const float tot = red[0] + red[1] + red[2] + red[3];
    const float rs = rsqrtf(tot * (1.0f / D_MODEL) + EPS);
    const float4 gg = reinterpret_cast<const float4*>(g)[tid];
    bf16* o = hn + (size_t)row * D_MODEL + tid * 4;
    o[0] = __float2bfloat16(x.x * rs * gg.x);
    o[1] = __float2bfloat16(x.y * rs * gg.y);
    o[2] = __float2bfloat16(x.z * rs * gg.z);
    o[3] = __float2bfloat16(x.w * rs * gg.w);
}

// ------------- pack wq|wk|wv fp32 [K][N] -> bf16 dst[3072][1024] (transposed) -------------
__global__ __launch_bounds__(256) void k_packT3(const float* __restrict__ wq,
                                                const float* __restrict__ wk,
                                                const float* __restrict__ wv,
                                                bf16* __restrict__ dst) {
    __shared__ float t[32][33];
    const int kt = blockIdx.x * 32;
    const int nt = blockIdx.y * 32;
    const float* W = (blockIdx.y < 32) ? wq : (blockIdx.y < 64) ? wk : wv;
    const int nl = nt & (D_MODEL - 1);
    const int tx = threadIdx.x, ty = threadIdx.y;
#pragma unroll
    for (int i = 0; i < 4; i++)
        t[ty + 8 * i][tx] = W[(size_t)(kt + ty + 8 * i) * D_MODEL + nl + tx];
    __syncthreads();
#pragma unroll
    for (int i = 0; i < 4; i++)
        dst[(size_t)(nt + ty + 8 * i) * D_MODEL + kt + tx] = __float2bfloat16(t[tx][ty + 8 * i]);
}

__global__ __launch_bounds__(256) void k_packT1(const float* __restrict__ w,
                                                bf16* __restrict__ dst) {
    __shared__ float t[32][33];
    const int kt = blockIdx.x * 32;
    const int nt = blockIdx.y * 32;
    const int tx = threadIdx.x, ty = threadIdx.y;
#pragma unroll
    for (int i = 0; i < 4; i++)
        t[ty + 8 * i][tx] = w[(size_t)(kt + ty + 8 * i) * D_MODEL + nt + tx];
    __syncthreads();
#pragma unroll
    for (int i = 0; i < 4; i++)
        dst[(size_t)(nt + ty + 8 * i) * D_MODEL + kt + tx] = __float2bfloat16(t[tx][ty + 8 * i]);
}

// ------------- QKV GEMM 128x128 tile, BK=64, global_load_lds(16) -------------
// A: hn[4096][1024], Bt: wqkvT[3072][1024]. Outputs:
//   Q -> qb row-major [bh][s][64]
//   K -> kpk packed   [bh][jb=s/32][t=d/16][lane=(d>>3&1)*32 + s&31][e=d&7]
//   V -> vpk packed   [bh][tile=s/64][dblk=d/32][m=(s>>4)&3][lane=((s>>3)&1)*32 + d&31][e=s&7]
__global__ __launch_bounds__(256) void k_gemm128_qkv(const bf16* __restrict__ A,
                                                     const bf16* __restrict__ Bt,
                                                     const float* __restrict__ bq,
                                                     const float* __restrict__ bk,
                                                     const float* __restrict__ bv,
                                                     bf16* __restrict__ qb,
                                                     bf16* __restrict__ kpk,
                                                     bf16* __restrict__ vpk) {
    __shared__ __align__(16) char smem[32768];
    bf16(*As)[64] = (bf16(*)[64])smem;
    bf16(*Bs)[64] = (bf16(*)[64])(smem + 16384);
    bf16(*Cs)[128] = (bf16(*)[128])smem;
    const int tid = threadIdx.x;
    const int w = tid >> 6, lane = tid & 63, l16 = lane & 15, lq = lane >> 4;
    const int wr = w >> 1, wc = w & 1;
    const int row0 = blockIdx.y * 128, col0 = blockIdx.x * 128;
    const int grow = lane >> 3, gcol = (lane & 7) * 8;
    f32x4 acc[4][4];
#pragma unroll
    for (int i = 0; i < 4; i++)
#pragma unroll
        for (int j = 0; j < 4; j++) acc[i][j] = f32x4{0, 0, 0, 0};

    for (int kt = 0; kt < D_MODEL; kt += 64) {
#pragma unroll
        for (int j = 0; j < 4; j++)
            gld_lds16(A + (size_t)(row0 + (w * 4 + j) * 8 + grow) * D_MODEL + kt + gcol,
                      &As[(w * 4 + j) * 8][0]);
#pragma unroll
        for (int j = 0; j < 4; j++)
            gld_lds16(Bt + (size_t)(col0 + (w * 4 + j) * 8 + grow) * D_MODEL + kt + gcol,
                      &Bs[(w * 4 + j) * 8][0]);
        __syncthreads();
#pragma unroll
        for (int ks = 0; ks < 2; ks++) {
            s16x8 af[4], bfr[4];
#pragma unroll
            for (int mi = 0; mi < 4; mi++) af[mi] = ld8(&As[wr * 64 + mi * 16 + l16][ks * 32 + lq * 8]);
#pragma unroll
            for (int ni = 0; ni < 4; ni++) bfr[ni] = ld8(&Bs[wc * 64 + ni * 16 + l16][ks * 32 + lq * 8]);
#pragma unroll
            for (int mi = 0; mi < 4; mi++)
#pragma unroll
                for (int ni = 0; ni < 4; ni++)
                    acc[mi][ni] = __builtin_amdgcn_mfma_f32_16x16x32_bf16(af[mi], bfr[ni], acc[mi][ni], 0, 0, 0);
        }
        __syncthreads();
    }

    const int sect = col0 >> 10;
    const int b_ = row0 >> 11;
    if (sect == 2) {
        // V: direct packed stores, 8B each (4 consecutive s = 4 consecutive e)
        const int hi_s = (lq >> 1) & 1, e0 = (lq & 1) * 4;
#pragma unroll
        for (int ni = 0; ni < 4; ni++) {
            const int dglob = col0 + wc * 64 + ni * 16 + l16;
            const int head = (dglob >> 6) & (NH - 1);
            const int dd = dglob & 63;
            const float bs = bv[dglob & 1023];
            bf16* dstH = vpk + ((size_t)(b_ * NH + head) << 17);
#pragma unroll
            for (int mi = 0; mi < 4; mi++) {
                const int tileL = ((row0 & (SEQ - 1)) >> 6) + wr;
                size_t off = ((((size_t)(tileL * 2 + (dd >> 5)) * 4 + mi) * 64 + hi_s * 32 + (dd & 31)) << 3) + e0;
                uint2 pv;
                pv.x = cvtpk(acc[mi][ni][0] + bs, acc[mi][ni][1] + bs);
                pv.y = cvtpk(acc[mi][ni][2] + bs, acc[mi][ni][3] + bs);
                *reinterpret_cast<uint2*>(dstH + off) = pv;
            }
        }
        return;
    }
    // Q / K: restage through LDS for vector-chunk writes
    const float* bias = (sect == 0) ? bq : bk;
#pragma unroll
    for (int ni = 0; ni < 4; ni++) {
        const int cl = wc * 64 + ni * 16 + l16;
        const float bs = bias[(col0 & 1023) + cl];
#pragma unroll
        for (int mi = 0; mi < 4; mi++) {
            const int rl = wr * 64 + mi * 16 + lq * 4;
#pragma unroll
            for (int r = 0; r < 4; r++) Cs[rl + r][cl] = __float2bfloat16(acc[mi][ni][r] + bs);
        }
    }
    __syncthreads();
    const int row = tid >> 1, ch = tid & 1;
    const int sg = row0 + row, s_ = sg & (SEQ - 1);
    const int ncol0 = col0 + ch * 64;
    const int head = (ncol0 & 1023) >> 6;
    if (sect == 0) {
        bf16* dst = qb + (((size_t)(b_ * NH + head) * SEQ + s_) << 6);
#pragma unroll
        for (int c = 0; c < 8; c++)
            *reinterpret_cast<s16x8*>(dst + c * 8) = *reinterpret_cast<s16x8*>(&Cs[row][ch * 64 + c * 8]);
    } else {
        bf16* dst = kpk + ((size_t)(b_ * NH + head) << 17);
        const int jb = s_ >> 5, j31 = s_ & 31;
#pragma unroll
        for (int c = 0; c < 8; c++) {
            const int t = c >> 1, hi = c & 1;
            size_t off = (((size_t)(jb * 4 + t) * 64 + hi * 32 + j31) << 3);
            *reinterpret_cast<s16x8*>(dst + off) = *reinterpret_cast<s16x8*>(&Cs[row][ch * 64 + c * 8]);
        }
    }
}

// ------------- RoPE on q (row layout) + fold softmax scale 0.125 -------------
__global__ __launch_bounds__(256) void k_rope_q(bf16* __restrict__ q,
                                                const float2* __restrict__ tab) {
    const int idx = blockIdx.x * 256 + threadIdx.x;  // 262144
    const int g = idx & 3;
    const int s = (idx >> 2) & (SEQ - 1);
    const int bh = idx >> 13;
    bf16* p = q + (((size_t)bh * SEQ + s) << 6) + g * 8;
    const s16x8 x1v = ld8(p), x2v = ld8(p + 32);
    const float2* tb = tab + s * 32 + g * 8;
    u32 r1[4], r2[4];
#pragma unroll
    for (int e2 = 0; e2 < 4; e2++) {
        float a[2], b[2];
#pragma unroll
        for (int k = 0; k < 2; k++) {
            const int e = e2 * 2 + k;
            const float2 cs = tb[e];
            const float x1 = b2f(x1v[e]);
            const float x2 = b2f(x2v[e]);
            a[k] = (x1 * cs.x - x2 * cs.y) * 0.125f;
            b[k] = (x2 * cs.x + x1 * cs.y) * 0.125f;
        }
        r1[e2] = cvtpk(a[0], a[1]);
        r2[e2] = cvtpk(b[0], b[1]);
    }
    *reinterpret_cast<uint4*>(p)      = *reinterpret_cast<uint4*>(r1);
    *reinterpret_cast<uint4*>(p + 32) = *reinterpret_cast<uint4*>(r2);
}

// ------------- RoPE on packed K, in place -------------
__global__ __launch_bounds__(256) void k_rope_kp(bf16* __restrict__ kpk,
                                                 const float2* __restrict__ tab) {
    const int idx = blockIdx.x * 256 + threadIdx.x;  // 131072
    const int lane = idx & 63;
    const int jb = (idx >> 6) & 63;
    const int bh = idx >> 12;
    const int j31 = lane & 31, hi = lane >> 5;
    const int s = jb * 32 + j31;
    bf16* base = kpk + ((size_t)bh << 17) + (((size_t)(jb * 4) * 64 + lane) << 3);
    s16x8 t0 = ld8(base), t1 = ld8(base + 512), t2 = ld8(base + 1024), t3 = ld8(base + 1536);
    const float2* tb0 = tab + s * 32 + 8 * hi;
    const float2* tb1 = tb0 + 16;
    u32 o0[4], o1[4], o2[4], o3[4];
#pragma unroll
    for (int e2 = 0; e2 < 4; e2++) {
        float v0_[2], v1_[2], v2_[2], v3_[2];
#pragma unroll
        for (int k = 0; k < 2; k++) {
            const int e = e2 * 2 + k;
            const float2 c0 = tb0[e], c1 = tb1[e];
            const float a0 = b2f(t0[e]);
            const float a2 = b2f(t2[e]);
            const float a1 = b2f(t1[e]);
            const float a3 = b2f(t3[e]);
            v0_[k] = a0 * c0.x - a2 * c0.y;
            v2_[k] = a2 * c0.x + a0 * c0.y;
            v1_[k] = a1 * c1.x - a3 * c1.y;
            v3_[k] = a3 * c1.x + a1 * c1.y;
        }
        o0[e2] = cvtpk(v0_[0], v0_[1]);
        o1[e2] = cvtpk(v1_[0], v1_[1]);
        o2[e2] = cvtpk(v2_[0], v2_[1]);
        o3[e2] = cvtpk(v3_[0], v3_[1]);
    }
    *reinterpret_cast<uint4*>(base)        = *reinterpret_cast<uint4*>(o0);
    *reinterpret_cast<uint4*>(base + 512)  = *reinterpret_cast<uint4*>(o1);
    *reinterpret_cast<uint4*>(base + 1024) = *reinterpret_cast<uint4*>(o2);
    *reinterpret_cast<uint4*>(base + 1536) = *reinterpret_cast<uint4*>(o3);
}

// ------------- causal flash attention, packed K/V, coalesced loads -------------
__global__ __launch_bounds__(256) void k_attn3(const bf16* __restrict__ qg,
                                               const bf16* __restrict__ kp,
                                               const bf16* __restrict__ vp,
                                               bf16* __restrict__ ao) {
    const int tid = threadIdx.x;
    const int w = tid >> 6;
    const int lane = tid & 63;
    const int l31 = lane & 31;
    const int hi = lane >> 5;
    const int bh = blockIdx.y;
    const int blk = blockIdx.x;
    int pos;
    switch (w) {
        case 0:  pos = blk;      break;
        case 1:  pos = 31 - blk; break;
        case 2:  pos = 32 + blk; break;
        default: pos = 63 - blk; break;
    }
    const int qw = pos << 5;
    const int qrow = qw + l31;

    const bf16* qptr = qg + (((size_t)bh * SEQ + qrow) << 6) + 8 * hi;
    s16x8 qf[4];
#pragma unroll
    for (int t = 0; t < 4; t++) qf[t] = ld8(qptr + 16 * t);

    f32x16 o0, o1;
#pragma unroll
    for (int r = 0; r < 16; r++) { o0[r] = 0.0f; o1[r] = 0.0f; }
    float m_run = -1e30f, l_run = 0.0f;

    const int nfull = qw >> 6;
    const int ntot  = (qw + 95) >> 6;
    const bf16* kbase = kp + ((size_t)bh << 17);
    const bf16* vbase = vp + ((size_t)bh << 17);

    for (int kt = 0; kt < ntot; kt++) {
        const int kb = kt << 6;
        f32x16 s0, s1;
#pragma unroll
        for (int r = 0; r < 16; r++) { s0[r] = 0.0f; s1[r] = 0.0f; }
#pragma unroll
        for (int t = 0; t < 4; t++) {
            const s16x8 kf0 = ld8(kbase + (((size_t)(kt * 8 + t) * 64 + lane) << 3));
            const s16x8 kf1 = ld8(kbase + (((size_t)(kt * 8 + 4 + t) * 64 + lane) << 3));
            s0 = __builtin_amdgcn_mfma_f32_32x32x16_bf16(kf0, qf[t], s0, 0, 0, 0);
            s1 = __builtin_amdgcn_mfma_f32_32x32x16_bf16(kf1, qf[t], s1, 0, 0, 0);
        }
        float p[32];
#pragma unroll
        for (int r = 0; r < 16; r++) { p[r] = s0[r]; p[16 + r] = s1[r]; }
        if (kt >= nfull) {
#pragma unroll
            for (int r = 0; r < 32; r++) {
                const int j = kb + 8 * (r >> 2) + (r & 3) + 4 * hi;
                if (j > qrow) p[r] = -3.0e38f;
            }
        }
        // tree max (dep depth ~5)
        float m16[16];
#pragma unroll
        for (int r = 0; r < 16; r++) m16[r] = fmaxf(p[r], p[r + 16]);
#pragma unroll
        for (int r = 0; r < 8; r++) m16[r] = fmaxf(m16[r], m16[r + 8]);
#pragma unroll
        for (int r = 0; r < 4; r++) m16[r] = fmaxf(m16[r], m16[r + 4]);
        float mx = fmaxf(fmaxf(m16[0], m16[1]), fmaxf(m16[2], m16[3]));
        mx = fmaxf(mx, __shfl_xor(mx, 32));
        if (!__all(mx <= m_run + 8.0f)) {   // defer-max (T13)
            const float mn = fmaxf(m_run, mx);
            const float alpha = __expf(m_run - mn);
            m_run = mn;
            l_run *= alpha;
#pragma unroll
            for (int r = 0; r < 16; r++) { o0[r] *= alpha; o1[r] *= alpha; }
        }
        float s4[4] = {0, 0, 0, 0};
#pragma unroll
        for (int r = 0; r < 32; r++) { p[r] = __expf(p[r] - m_run); s4[r & 3] += p[r]; }
        float rs = (s4[0] + s4[1]) + (s4[2] + s4[3]);
        rs += __shfl_xor(rs, 32);
        l_run += rs;
        // P^T -> B-fragments (T12)
        u32 pk_[16];
#pragma unroll
        for (int a = 0; a < 8; a++) {
            pk_[2 * a]     = cvtpk(p[4 * a],     p[4 * a + 1]);
            pk_[2 * a + 1] = cvtpk(p[4 * a + 2], p[4 * a + 3]);
        }
#pragma unroll
        for (int m = 0; m < 4; m++) {
            u32 b0 = pk_[4 * m],     b2 = pk_[4 * m + 2];
            u32 b1 = pk_[4 * m + 1], b3 = pk_[4 * m + 3];
            swap32(b0, b2);
            swap32(b1, b3);
            W4 B; B.w[0] = b0; B.w[1] = b1; B.w[2] = b2; B.w[3] = b3;
            const s16x8 v0 = ld8(vbase + (((size_t)(kt * 8 + m) * 64 + lane) << 3));
            const s16x8 v1 = ld8(vbase + (((size_t)(kt * 8 + 4 + m) * 64 + lane) << 3));
            o0 = __builtin_amdgcn_mfma_f32_32x32x16_bf16(v0, B.v, o0, 0, 0, 0);
            o1 = __builtin_amdgcn_mfma_f32_32x32x16_bf16(v1, B.v, o1, 0, 0, 0);
        }
    }
    const float inv = 1.0f / l_run;
    const int b_ = bh >> 4, h_ = bh & (NH - 1);
    bf16* orow = ao + (((size_t)(b_ * SEQ + qrow)) << 10) + (h_ << 6);
#pragma unroll
    for (int g = 0; g < 4; g++) {
        {
            uint2 val;
            val.x = cvtpk(o0[4 * g] * inv, o0[4 * g + 1] * inv);
            val.y = cvtpk(o0[4 * g + 2] * inv, o0[4 * g + 3] * inv);
            *reinterpret_cast<uint2*>(orow + 8 * g + 4 * hi) = val;
        }
        {
            uint2 val;
            val.x = cvtpk(o1[4 * g] * inv, o1[4 * g + 1] * inv);
            val.y = cvtpk(o1[4 * g + 2] * inv, o1[4 * g + 3] * inv);
            *reinterpret_cast<uint2*>(orow + 32 + 8 * g + 4 * hi) = val;
        }
    }
}

// ------------- O-proj GEMM 128x128 + bias + residual -> fp32 out -------------
__global__ __launch_bounds__(256) void k_gemm128_out(const bf16* __restrict__ A,
                                                     const bf16* __restrict__ Bt,
                                                     const float* __restrict__ bo,
                                                     const float* __restrict__ hres,
                                                     float* __restrict__ out) {
    __shared__ __align__(16) char smem[32768];
    bf16(*As)[64] = (bf16(*)[64])smem;
    bf16(*Bs)[64] = (bf16(*)[64])(smem + 16384);
    const int tid = threadIdx.x;
    const int w = tid >> 6, lane = tid & 63, l16 = lane & 15, lq = lane >> 4;
    const int wr = w >> 1, wc = w & 1;
    const int row0 = blockIdx.y * 128, col0 = blockIdx.x * 128;
    const int grow = lane >> 3, gcol = (lane & 7) * 8;
    f32x4 acc[4][4];
#pragma unroll
    for (int i = 0; i < 4; i++)
#pragma unroll
        for (int j = 0; j < 4; j++) acc[i][j] = f32x4{0, 0, 0, 0};

    for (int kt = 0; kt < D_MODEL; kt += 64) {
#pragma unroll
        for (int j = 0; j < 4; j++)
            gld_lds16(A + (size_t)(row0 + (w * 4 + j) * 8 + grow) * D_MODEL + kt + gcol,
                      &As[(w * 4 + j) * 8][0]);
#pragma unroll
        for (int j = 0; j < 4; j++)
            gld_lds16(Bt + (size_t)(col0 + (w * 4 + j) * 8 + grow) * D_MODEL + kt + gcol,
                      &Bs[(w * 4 + j) * 8][0]);
        __syncthreads();
#pragma unroll
        for (int ks = 0; ks < 2; ks++) {
            s16x8 af[4], bfr[4];
#pragma unroll
            for (int mi = 0; mi < 4; mi++) af[mi] = ld8(&As[wr * 64 + mi * 16 + l16][ks * 32 + lq * 8]);
#pragma unroll
            for (int ni = 0; ni < 4; ni++) bfr[ni] = ld8(&Bs[wc * 64 + ni * 16 + l16][ks * 32 + lq * 8]);
#pragma unroll
            for (int mi = 0; mi < 4; mi++)
#pragma unroll
                for (int ni = 0; ni < 4; ni++)
                    acc[mi][ni] = __builtin_amdgcn_mfma_f32_16x16x32_bf16(af[mi], bfr[ni], acc[mi][ni], 0, 0, 0);
        }
        __syncthreads();
    }
#pragma unroll
    for (int ni = 0; ni < 4; ni++) {
        const int col = col0 + wc * 64 + ni * 16 + l16;
        const float bs = bo[col];
#pragma unroll
        for (int mi = 0; mi < 4; mi++) {
#pragma unroll
            for (int r = 0; r < 4; r++) {
                const int row = row0 + wr * 64 + mi * 16 + lq * 4 + r;
                out[(size_t)row * D_MODEL + col] =
                    acc[mi][ni][r] + bs + hres[(size_t)row * D_MODEL + col];
            }
        }
    }
}

extern "C" void kernel_launch(void* const* d_in, const int* in_sizes, int n_in,
                              void* d_out, int out_size, void* d_ws, size_t ws_size,
                              hipStream_t stream) {
    (void)in_sizes; (void)n_in; (void)out_size; (void)ws_size;
    const float* h  = (const float*)d_in[0];
    const float* wq = (const float*)d_in[1];
    const float* bq = (const float*)d_in[2];
    const float* wk = (const float*)d_in[3];
    const float* bk = (const float*)d_in[4];
    const float* wv = (const float*)d_in[5];
    const float* bv = (const float*)d_in[6];
    const float* wo = (const float*)d_in[7];
    const float* bo = (const float*)d_in[8];
    const float* g  = (const float*)d_in[9];
    float* out = (float*)d_out;

    char* ws = (char*)d_ws;
    size_t off = 0;
    auto carve = [&](size_t bytes) {
        void* p = ws + off;
        off += (bytes + 255) & ~(size_t)255;
        return p;
    };
    bf16* hn    = (bf16*)carve((size_t)NTOK * D_MODEL * 2);
    bf16* wqkvT = (bf16*)carve((size_t)3 * D_MODEL * D_MODEL * 2);
    bf16* woT   = (bf16*)carve((size_t)D_MODEL * D_MODEL * 2);
    bf16* qb    = (bf16*)carve((size_t)BATCH * NH * SEQ * DK * 2);
    bf16* kpk   = (bf16*)carve((size_t)BATCH * NH * SEQ * DK * 2);
    bf16* vpk   = (bf16*)carve((size_t)BATCH * NH * SEQ * DK * 2);
    bf16* ao    = (bf16*)carve((size_t)NTOK * D_MODEL * 2);
    float2* tab = (float2*)carve((size_t)SEQ * 32 * sizeof(float2));

    k_tab<<<256, 256, 0, stream>>>(tab);
    k_rmsnorm<<<NTOK, 256, 0, stream>>>(h, g, hn);
    k_packT3<<<dim3(32, 96), dim3(32, 8), 0, stream>>>(wq, wk, wv, wqkvT);
    k_packT1<<<dim3(32, 32), dim3(32, 8), 0, stream>>>(wo, woT);
    k_gemm128_qkv<<<dim3(24, 32), 256, 0, stream>>>(hn, wqkvT, bq, bk, bv, qb, kpk, vpk);
    k_rope_q<<<1024, 256, 0, stream>>>(qb, tab);
    k_rope_kp<<<512, 256, 0, stream>>>(kpk, tab);
    k_attn3<<<dim3(16, BATCH * NH), 256, 0, stream>>>(qb, kpk, vpk, ao);
    k_gemm128_out<<<dim3(8, 32), 256, 0, stream>>>(ao, woT, bo, h, out);
}

// Round 5
// 153.658 us; speedup vs baseline: 1.8778x; 1.1868x over previous
//
#include <hip/hip_runtime.h>
#include <hip/hip_bf16.h>

#define D_MODEL 1024
#define NH 16
#define DK 64
#define SEQ 2048
#define BATCH 2
#define NTOK (BATCH * SEQ)   // 4096
#define EPS 1e-6f

typedef __attribute__((ext_vector_type(4))) float f32x4;
typedef __attribute__((ext_vector_type(16))) float f32x16;
typedef __attribute__((ext_vector_type(8))) short s16x8;
typedef unsigned int u32;
typedef __hip_bfloat16 bf16;

#define AS1 __attribute__((address_space(1)))
#define AS3 __attribute__((address_space(3)))

static __device__ __forceinline__ s16x8 ld8(const bf16* p) {
    return *reinterpret_cast<const s16x8*>(p);
}
// bf16 bits (in a short) -> float, no address-of
static __device__ __forceinline__ float b2f(short s) {
    return __uint_as_float(((u32)(unsigned short)s) << 16);
}

static __device__ __forceinline__ u32 cvtpk(float lo, float hi) {
    u32 r;
    asm volatile("v_cvt_pk_bf16_f32 %0, %1, %2" : "=v"(r) : "v"(lo), "v"(hi));
    return r;
}
static __device__ __forceinline__ void swap32(u32& a, u32& b) {
    asm volatile("v_permlane32_swap_b32 %0, %1" : "+v"(a), "+v"(b));
}
// hardware exp2 (v_exp_f32 computes 2^x); pure asm so it can schedule/CSE
static __device__ __forceinline__ float exp2f_fast(float x) {
    float r;
    asm("v_exp_f32 %0, %1" : "=v"(r) : "v"(x));
    return r;
}
// async global->LDS, 16B per lane; lds dest must be wave-uniform base (HW adds lane*16)
static __device__ __forceinline__ void gld_lds16(const bf16* g, bf16* l) {
    __builtin_amdgcn_global_load_lds((const AS1 void*)g, (AS3 void*)l, 16, 0, 0);
}

union W4 { s16x8 v; u32 w[4]; };

// ---------------- cos/sin table: tab[s][i] for s<2048, i<32 ----------------
__global__ __launch_bounds__(256) void k_tab(float2* __restrict__ tab) {
    const int idx = blockIdx.x * 256 + threadIdx.x;   // 65536
    const int s = idx >> 5, i = idx & 31;
    const float theta = __expf(-(float)i * 0.28782313662425572f);  // ln(10000)/32
    float sn, cs;
    sincosf((float)s * theta, &sn, &cs);
    tab[idx] = make_float2(cs, sn);
}

// ---------------- RMSNorm: h[4096][1024] fp32 -> hn bf16 ----------------
__global__ __launch_bounds__(256) void k_rmsnorm(const float* __restrict__ h,
                                                 const float* __restrict__ g,
                                                 bf16* __restrict__ hn) {
    const int row = blockIdx.x;
    const int tid = threadIdx.x;
    const float4 x = reinterpret_cast<const float4*>(h + (size_t)row * D_MODEL)[tid];
    float ss = x.x * x.x + x.y * x.y + x.z * x.z + x.w * x.w;
#pragma unroll
    for (int off = 32; off; off >>= 1) ss += __shfl_xor(ss, off);
    __shared__ float red[4];
    if ((tid & 63) == 0) red[tid >> 6] = ss;
    __syncthreads();
    const float tot = red[0] + red[1] + red[2] + red[3];
    const float rs = rsqrtf(tot * (1.0f / D_MODEL) + EPS);
    const float4 gg = reinterpret_cast<const float4*>(g)[tid];
    bf16* o = hn + (size_t)row * D_MODEL + tid * 4;
    o[0] = __float2bfloat16(x.x * rs * gg.x);
    o[1] = __float2bfloat16(x.y * rs * gg.y);
    o[2] = __float2bfloat16(x.z * rs * gg.z);
    o[3] = __float2bfloat16(x.w * rs * gg.w);
}

// ------------- pack wq|wk|wv fp32 [K][N] -> bf16 dst[3072][1024] (transposed) -------------
__global__ __launch_bounds__(256) void k_packT3(const float* __restrict__ wq,
                                                const float* __restrict__ wk,
                                                const float* __restrict__ wv,
                                                bf16* __restrict__ dst) {
    __shared__ float t[32][33];
    const int kt = blockIdx.x * 32;
    const int nt = blockIdx.y * 32;
    const float* W = (blockIdx.y < 32) ? wq : (blockIdx.y < 64) ? wk : wv;
    const int nl = nt & (D_MODEL - 1);
    const int tx = threadIdx.x, ty = threadIdx.y;
#pragma unroll
    for (int i = 0; i < 4; i++)
        t[ty + 8 * i][tx] = W[(size_t)(kt + ty + 8 * i) * D_MODEL + nl + tx];
    __syncthreads();
#pragma unroll
    for (int i = 0; i < 4; i++)
        dst[(size_t)(nt + ty + 8 * i) * D_MODEL + kt + tx] = __float2bfloat16(t[tx][ty + 8 * i]);
}

__global__ __launch_bounds__(256) void k_packT1(const float* __restrict__ w,
                                                bf16* __restrict__ dst) {
    __shared__ float t[32][33];
    const int kt = blockIdx.x * 32;
    const int nt = blockIdx.y * 32;
    const int tx = threadIdx.x, ty = threadIdx.y;
#pragma unroll
    for (int i = 0; i < 4; i++)
        t[ty + 8 * i][tx] = w[(size_t)(kt + ty + 8 * i) * D_MODEL + nt + tx];
    __syncthreads();
#pragma unroll
    for (int i = 0; i < 4; i++)
        dst[(size_t)(nt + ty + 8 * i) * D_MODEL + kt + tx] = __float2bfloat16(t[tx][ty + 8 * i]);
}

// ------------- QKV GEMM 128x128 tile, BK=64, global_load_lds(16) -------------
// A: hn[4096][1024], Bt: wqkvT[3072][1024]. Outputs:
//   Q -> qb row-major [bh][s][64]
//   K -> kpk packed   [bh][jb=s/32][t=d/16][lane=(d>>3&1)*32 + s&31][e=d&7]
//   V -> vpk packed   [bh][tile=s/64][dblk=d/32][m=(s>>4)&3][lane=((s>>3)&1)*32 + d&31][e=s&7]
__global__ __launch_bounds__(256) void k_gemm128_qkv(const bf16* __restrict__ A,
                                                     const bf16* __restrict__ Bt,
                                                     const float* __restrict__ bq,
                                                     const float* __restrict__ bk,
                                                     const float* __restrict__ bv,
                                                     bf16* __restrict__ qb,
                                                     bf16* __restrict__ kpk,
                                                     bf16* __restrict__ vpk) {
    __shared__ __align__(16) char smem[32768];
    bf16(*As)[64] = (bf16(*)[64])smem;
    bf16(*Bs)[64] = (bf16(*)[64])(smem + 16384);
    bf16(*Cs)[128] = (bf16(*)[128])smem;
    const int tid = threadIdx.x;
    const int w = tid >> 6, lane = tid & 63, l16 = lane & 15, lq = lane >> 4;
    const int wr = w >> 1, wc = w & 1;
    const int row0 = blockIdx.y * 128, col0 = blockIdx.x * 128;
    const int grow = lane >> 3, gcol = (lane & 7) * 8;
    f32x4 acc[4][4];
#pragma unroll
    for (int i = 0; i < 4; i++)
#pragma unroll
        for (int j = 0; j < 4; j++) acc[i][j] = f32x4{0, 0, 0, 0};

    for (int kt = 0; kt < D_MODEL; kt += 64) {
#pragma unroll
        for (int j = 0; j < 4; j++)
            gld_lds16(A + (size_t)(row0 + (w * 4 + j) * 8 + grow) * D_MODEL + kt + gcol,
                      &As[(w * 4 + j) * 8][0]);
#pragma unroll
        for (int j = 0; j < 4; j++)
            gld_lds16(Bt + (size_t)(col0 + (w * 4 + j) * 8 + grow) * D_MODEL + kt + gcol,
                      &Bs[(w * 4 + j) * 8][0]);
        __syncthreads();
#pragma unroll
        for (int ks = 0; ks < 2; ks++) {
            s16x8 af[4], bfr[4];
#pragma unroll
            for (int mi = 0; mi < 4; mi++) af[mi] = ld8(&As[wr * 64 + mi * 16 + l16][ks * 32 + lq * 8]);
#pragma unroll
            for (int ni = 0; ni < 4; ni++) bfr[ni] = ld8(&Bs[wc * 64 + ni * 16 + l16][ks * 32 + lq * 8]);
#pragma unroll
            for (int mi = 0; mi < 4; mi++)
#pragma unroll
                for (int ni = 0; ni < 4; ni++)
                    acc[mi][ni] = __builtin_amdgcn_mfma_f32_16x16x32_bf16(af[mi], bfr[ni], acc[mi][ni], 0, 0, 0);
        }
        __syncthreads();
    }

    const int sect = col0 >> 10;
    const int b_ = row0 >> 11;
    if (sect == 2) {
        // V: direct packed stores, 8B each (4 consecutive s = 4 consecutive e)
        const int hi_s = (lq >> 1) & 1, e0 = (lq & 1) * 4;
#pragma unroll
        for (int ni = 0; ni < 4; ni++) {
            const int dglob = col0 + wc * 64 + ni * 16 + l16;
            const int head = (dglob >> 6) & (NH - 1);
            const int dd = dglob & 63;
            const float bs = bv[dglob & 1023];
            bf16* dstH = vpk + ((size_t)(b_ * NH + head) << 17);
#pragma unroll
            for (int mi = 0; mi < 4; mi++) {
                const int tileL = ((row0 & (SEQ - 1)) >> 6) + wr;
                size_t off = ((((size_t)(tileL * 2 + (dd >> 5)) * 4 + mi) * 64 + hi_s * 32 + (dd & 31)) << 3) + e0;
                uint2 pv;
                pv.x = cvtpk(acc[mi][ni][0] + bs, acc[mi][ni][1] + bs);
                pv.y = cvtpk(acc[mi][ni][2] + bs, acc[mi][ni][3] + bs);
                *reinterpret_cast<uint2*>(dstH + off) = pv;
            }
        }
        return;
    }
    // Q / K: restage through LDS for vector-chunk writes
    const float* bias = (sect == 0) ? bq : bk;
#pragma unroll
    for (int ni = 0; ni < 4; ni++) {
        const int cl = wc * 64 + ni * 16 + l16;
        const float bs = bias[(col0 & 1023) + cl];
#pragma unroll
        for (int mi = 0; mi < 4; mi++) {
            const int rl = wr * 64 + mi * 16 + lq * 4;
#pragma unroll
            for (int r = 0; r < 4; r++) Cs[rl + r][cl] = __float2bfloat16(acc[mi][ni][r] + bs);
        }
    }
    __syncthreads();
    const int row = tid >> 1, ch = tid & 1;
    const int sg = row0 + row, s_ = sg & (SEQ - 1);
    const int ncol0 = col0 + ch * 64;
    const int head = (ncol0 & 1023) >> 6;
    if (sect == 0) {
        bf16* dst = qb + (((size_t)(b_ * NH + head) * SEQ + s_) << 6);
#pragma unroll
        for (int c = 0; c < 8; c++)
            *reinterpret_cast<s16x8*>(dst + c * 8) = *reinterpret_cast<s16x8*>(&Cs[row][ch * 64 + c * 8]);
    } else {
        bf16* dst = kpk + ((size_t)(b_ * NH + head) << 17);
        const int jb = s_ >> 5, j31 = s_ & 31;
#pragma unroll
        for (int c = 0; c < 8; c++) {
            const int t = c >> 1, hi = c & 1;
            size_t off = (((size_t)(jb * 4 + t) * 64 + hi * 32 + j31) << 3);
            *reinterpret_cast<s16x8*>(dst + off) = *reinterpret_cast<s16x8*>(&Cs[row][ch * 64 + c * 8]);
        }
    }
}

// ------------- RoPE on q (row layout) + fold softmax_scale*log2e (exp2-domain) -------------
__global__ __launch_bounds__(256) void k_rope_q(bf16* __restrict__ q,
                                                const float2* __restrict__ tab) {
    const int idx = blockIdx.x * 256 + threadIdx.x;  // 262144
    const int g = idx & 3;
    const int s = (idx >> 2) & (SEQ - 1);
    const int bh = idx >> 13;
    bf16* p = q + (((size_t)bh * SEQ + s) << 6) + g * 8;
    const s16x8 x1v = ld8(p), x2v = ld8(p + 32);
    const float2* tb = tab + s * 32 + g * 8;
    u32 r1[4], r2[4];
#pragma unroll
    for (int e2 = 0; e2 < 4; e2++) {
        float a[2], b[2];
#pragma unroll
        for (int k = 0; k < 2; k++) {
            const int e = e2 * 2 + k;
            const float2 cs = tb[e];
            const float x1 = b2f(x1v[e]);
            const float x2 = b2f(x2v[e]);
            a[k] = (x1 * cs.x - x2 * cs.y) * 0.18033688011112042f;  // 0.125*log2(e)
            b[k] = (x2 * cs.x + x1 * cs.y) * 0.18033688011112042f;
        }
        r1[e2] = cvtpk(a[0], a[1]);
        r2[e2] = cvtpk(b[0], b[1]);
    }
    *reinterpret_cast<uint4*>(p)      = *reinterpret_cast<uint4*>(r1);
    *reinterpret_cast<uint4*>(p + 32) = *reinterpret_cast<uint4*>(r2);
}

// ------------- RoPE on packed K, in place -------------
__global__ __launch_bounds__(256) void k_rope_kp(bf16* __restrict__ kpk,
                                                 const float2* __restrict__ tab) {
    const int idx = blockIdx.x * 256 + threadIdx.x;  // 131072
    const int lane = idx & 63;
    const int jb = (idx >> 6) & 63;
    const int bh = idx >> 12;
    const int j31 = lane & 31, hi = lane >> 5;
    const int s = jb * 32 + j31;
    bf16* base = kpk + ((size_t)bh << 17) + (((size_t)(jb * 4) * 64 + lane) << 3);
    s16x8 t0 = ld8(base), t1 = ld8(base + 512), t2 = ld8(base + 1024), t3 = ld8(base + 1536);
    const float2* tb0 = tab + s * 32 + 8 * hi;
    const float2* tb1 = tb0 + 16;
    u32 o0[4], o1[4], o2[4], o3[4];
#pragma unroll
    for (int e2 = 0; e2 < 4; e2++) {
        float v0_[2], v1_[2], v2_[2], v3_[2];
#pragma unroll
        for (int k = 0; k < 2; k++) {
            const int e = e2 * 2 + k;
            const float2 c0 = tb0[e], c1 = tb1[e];
            const float a0 = b2f(t0[e]);
            const float a2 = b2f(t2[e]);
            const float a1 = b2f(t1[e]);
            const float a3 = b2f(t3[e]);
            v0_[k] = a0 * c0.x - a2 * c0.y;
            v2_[k] = a2 * c0.x + a0 * c0.y;
            v1_[k] = a1 * c1.x - a3 * c1.y;
            v3_[k] = a3 * c1.x + a1 * c1.y;
        }
        o0[e2] = cvtpk(v0_[0], v0_[1]);
        o1[e2] = cvtpk(v1_[0], v1_[1]);
        o2[e2] = cvtpk(v2_[0], v2_[1]);
        o3[e2] = cvtpk(v3_[0], v3_[1]);
    }
    *reinterpret_cast<uint4*>(base)        = *reinterpret_cast<uint4*>(o0);
    *reinterpret_cast<uint4*>(base + 512)  = *reinterpret_cast<uint4*>(o1);
    *reinterpret_cast<uint4*>(base + 1024) = *reinterpret_cast<uint4*>(o2);
    *reinterpret_cast<uint4*>(base + 1536) = *reinterpret_cast<uint4*>(o3);
}

// ------------- causal flash attention: pipelined, XCD-local, exp2 softmax -------------
__global__ __launch_bounds__(256) void k_attn4(const bf16* __restrict__ qg,
                                               const bf16* __restrict__ kp,
                                               const bf16* __restrict__ vp,
                                               bf16* __restrict__ ao) {
    const int tid = threadIdx.x;
    const int w = tid >> 6;
    const int lane = tid & 63;
    const int l31 = lane & 31;
    const int hi = lane >> 5;
    // XCD swizzle: all 16 q-blocks of a head share bid%8 (one XCD's L2 holds the head's K/V)
    const int bid = blockIdx.x;          // 0..511
    const int blk = (bid >> 3) & 15;
    const int bh  = (bid & 7) + ((bid >> 7) << 3);
    int pos;
    switch (w) {
        case 0:  pos = blk;      break;
        case 1:  pos = 31 - blk; break;
        case 2:  pos = 32 + blk; break;
        default: pos = 63 - blk; break;
    }
    const int qw = pos << 5;
    const int qrow = qw + l31;

    const bf16* qptr = qg + (((size_t)bh * SEQ + qrow) << 6) + 8 * hi;
    s16x8 qf[4];
#pragma unroll
    for (int t = 0; t < 4; t++) qf[t] = ld8(qptr + 16 * t);

    f32x16 o0, o1;
#pragma unroll
    for (int r = 0; r < 16; r++) { o0[r] = 0.0f; o1[r] = 0.0f; }
    float m_run = -1e30f, l_run = 0.0f;

    const int nfull = qw >> 6;
    const int ntot  = (qw + 95) >> 6;
    const bf16* kbase = kp + ((size_t)bh << 17);
    const bf16* vbase = vp + ((size_t)bh << 17);

    s16x8 kA[8], kB[8], vC[8];
#pragma unroll
    for (int t = 0; t < 8; t++) kA[t] = ld8(kbase + (((size_t)t * 64 + lane) << 3));

    auto att_step = [&](s16x8(&KC)[8], s16x8(&KN)[8], const int kt) {
        const int kb = kt << 6;
        // V(kt) loads issue first — latency hides under QK^T + softmax
#pragma unroll
        for (int t = 0; t < 8; t++)
            vC[t] = ld8(vbase + (((size_t)(kt * 8 + t) * 64 + lane) << 3));
        f32x16 s0, s1;
#pragma unroll
        for (int r = 0; r < 16; r++) { s0[r] = 0.0f; s1[r] = 0.0f; }
        __builtin_amdgcn_s_setprio(1);
#pragma unroll
        for (int t = 0; t < 4; t++) {
            s0 = __builtin_amdgcn_mfma_f32_32x32x16_bf16(KC[t],     qf[t], s0, 0, 0, 0);
            s1 = __builtin_amdgcn_mfma_f32_32x32x16_bf16(KC[4 + t], qf[t], s1, 0, 0, 0);
        }
        __builtin_amdgcn_s_setprio(0);
        // prefetch K(kt+1) — hides under softmax + PV (clamped: last iter reload is harmless)
        const int ktn = (kt + 1 < ntot) ? kt + 1 : kt;
#pragma unroll
        for (int t = 0; t < 8; t++)
            KN[t] = ld8(kbase + (((size_t)(ktn * 8 + t) * 64 + lane) << 3));
        float p[32];
#pragma unroll
        for (int r = 0; r < 16; r++) { p[r] = s0[r]; p[16 + r] = s1[r]; }
        if (kt >= nfull) {
#pragma unroll
            for (int r = 0; r < 32; r++) {
                const int j = kb + 8 * (r >> 2) + (r & 3) + 4 * hi;
                if (j > qrow) p[r] = -3.0e38f;
            }
        }
        float m16[16];
#pragma unroll
        for (int r = 0; r < 16; r++) m16[r] = fmaxf(p[r], p[r + 16]);
#pragma unroll
        for (int r = 0; r < 8; r++) m16[r] = fmaxf(m16[r], m16[r + 8]);
#pragma unroll
        for (int r = 0; r < 4; r++) m16[r] = fmaxf(m16[r], m16[r + 4]);
        float mx = fmaxf(fmaxf(m16[0], m16[1]), fmaxf(m16[2], m16[3]));
        mx = fmaxf(mx, __shfl_xor(mx, 32));
        if (!__all(mx <= m_run + 8.0f)) {   // defer-max (T13), exp2-domain
            const float mn = fmaxf(m_run, mx);
            const float alpha = exp2f_fast(m_run - mn);
            m_run = mn;
            l_run *= alpha;
#pragma unroll
            for (int r = 0; r < 16; r++) { o0[r] *= alpha; o1[r] *= alpha; }
        }
        float s4[4] = {0, 0, 0, 0};
#pragma unroll
        for (int r = 0; r < 32; r++) { p[r] = exp2f_fast(p[r] - m_run); s4[r & 3] += p[r]; }
        float rs = (s4[0] + s4[1]) + (s4[2] + s4[3]);
        rs += __shfl_xor(rs, 32);
        l_run += rs;
        // P^T -> B-fragments (T12)
        u32 pk_[16];
#pragma unroll
        for (int a = 0; a < 8; a++) {
            pk_[2 * a]     = cvtpk(p[4 * a],     p[4 * a + 1]);
            pk_[2 * a + 1] = cvtpk(p[4 * a + 2], p[4 * a + 3]);
        }
        __builtin_amdgcn_s_setprio(1);
#pragma unroll
        for (int m = 0; m < 4; m++) {
            u32 b0 = pk_[4 * m],     b2 = pk_[4 * m + 2];
            u32 b1 = pk_[4 * m + 1], b3 = pk_[4 * m + 3];
            swap32(b0, b2);
            swap32(b1, b3);
            W4 B; B.w[0] = b0; B.w[1] = b1; B.w[2] = b2; B.w[3] = b3;
            o0 = __builtin_amdgcn_mfma_f32_32x32x16_bf16(vC[m],     B.v, o0, 0, 0, 0);
            o1 = __builtin_amdgcn_mfma_f32_32x32x16_bf16(vC[4 + m], B.v, o1, 0, 0, 0);
        }
        __builtin_amdgcn_s_setprio(0);
    };

    int kt = 0;
    for (;;) {
        att_step(kA, kB, kt); if (++kt == ntot) break;
        att_step(kB, kA, kt); if (++kt == ntot) break;
    }

    const float inv = 1.0f / l_run;
    const int b_ = bh >> 4, h_ = bh & (NH - 1);
    bf16* orow = ao + (((size_t)(b_ * SEQ + qrow)) << 10) + (h_ << 6);
#pragma unroll
    for (int g = 0; g < 4; g++) {
        {
            uint2 val;
            val.x = cvtpk(o0[4 * g] * inv, o0[4 * g + 1] * inv);
            val.y = cvtpk(o0[4 * g + 2] * inv, o0[4 * g + 3] * inv);
            *reinterpret_cast<uint2*>(orow + 8 * g + 4 * hi) = val;
        }
        {
            uint2 val;
            val.x = cvtpk(o1[4 * g] * inv, o1[4 * g + 1] * inv);
            val.y = cvtpk(o1[4 * g + 2] * inv, o1[4 * g + 3] * inv);
            *reinterpret_cast<uint2*>(orow + 32 + 8 * g + 4 * hi) = val;
        }
    }
}

// ------------- O-proj GEMM 128x128 + bias + residual -> fp32 out -------------
__global__ __launch_bounds__(256) void k_gemm128_out(const bf16* __restrict__ A,
                                                     const bf16* __restrict__ Bt,
                                                     const float* __restrict__ bo,
                                                     const float* __restrict__ hres,
                                                     float* __restrict__ out) {
    __shared__ __align__(16) char smem[32768];
    bf16(*As)[64] = (bf16(*)[64])smem;
    bf16(*Bs)[64] = (bf16(*)[64])(smem + 16384);
    const int tid = threadIdx.x;
    const int w = tid >> 6, lane = tid & 63, l16 = lane & 15, lq = lane >> 4;
    const int wr = w >> 1, wc = w & 1;
    const int row0 = blockIdx.y * 128, col0 = blockIdx.x * 128;
    const int grow = lane >> 3, gcol = (lane & 7) * 8;
    f32x4 acc[4][4];
#pragma unroll
    for (int i = 0; i < 4; i++)
#pragma unroll
        for (int j = 0; j < 4; j++) acc[i][j] = f32x4{0, 0, 0, 0};

    for (int kt = 0; kt < D_MODEL; kt += 64) {
#pragma unroll
        for (int j = 0; j < 4; j++)
            gld_lds16(A + (size_t)(row0 + (w * 4 + j) * 8 + grow) * D_MODEL + kt + gcol,
                      &As[(w * 4 + j) * 8][0]);
#pragma unroll
        for (int j = 0; j < 4; j++)
            gld_lds16(Bt + (size_t)(col0 + (w * 4 + j) * 8 + grow) * D_MODEL + kt + gcol,
                      &Bs[(w * 4 + j) * 8][0]);
        __syncthreads();
#pragma unroll
        for (int ks = 0; ks < 2; ks++) {
            s16x8 af[4], bfr[4];
#pragma unroll
            for (int mi = 0; mi < 4; mi++) af[mi] = ld8(&As[wr * 64 + mi * 16 + l16][ks * 32 + lq * 8]);
#pragma unroll
            for (int ni = 0; ni < 4; ni++) bfr[ni] = ld8(&Bs[wc * 64 + ni * 16 + l16][ks * 32 + lq * 8]);
#pragma unroll
            for (int mi = 0; mi < 4; mi++)
#pragma unroll
                for (int ni = 0; ni < 4; ni++)
                    acc[mi][ni] = __builtin_amdgcn_mfma_f32_16x16x32_bf16(af[mi], bfr[ni], acc[mi][ni], 0, 0, 0);
        }
        __syncthreads();
    }
#pragma unroll
    for (int ni = 0; ni < 4; ni++) {
        const int col = col0 + wc * 64 + ni * 16 + l16;
        const float bs = bo[col];
#pragma unroll
        for (int mi = 0; mi < 4; mi++) {
#pragma unroll
            for (int r = 0; r < 4; r++) {
                const int row = row0 + wr * 64 + mi * 16 + lq * 4 + r;
                out[(size_t)row * D_MODEL + col] =
                    acc[mi][ni][r] + bs + hres[(size_t)row * D_MODEL + col];
            }
        }
    }
}

extern "C" void kernel_launch(void* const* d_in, const int* in_sizes, int n_in,
                              void* d_out, int out_size, void* d_ws, size_t ws_size,
                              hipStream_t stream) {
    (void)in_sizes; (void)n_in; (void)out_size; (void)ws_size;
    const float* h  = (const float*)d_in[0];
    const float* wq = (const float*)d_in[1];
    const float* bq = (const float*)d_in[2];
    const float* wk = (const float*)d_in[3];
    const float* bk = (const float*)d_in[4];
    const float* wv = (const float*)d_in[5];
    const float* bv = (const float*)d_in[6];
    const float* wo = (const float*)d_in[7];
    const float* bo = (const float*)d_in[8];
    const float* g  = (const float*)d_in[9];
    float* out = (float*)d_out;

    char* ws = (char*)d_ws;
    size_t off = 0;
    auto carve = [&](size_t bytes) {
        void* p = ws + off;
        off += (bytes + 255) & ~(size_t)255;
        return p;
    };
    bf16* hn    = (bf16*)carve((size_t)NTOK * D_MODEL * 2);
    bf16* wqkvT = (bf16*)carve((size_t)3 * D_MODEL * D_MODEL * 2);
    bf16* woT   = (bf16*)carve((size_t)D_MODEL * D_MODEL * 2);
    bf16* qb    = (bf16*)carve((size_t)BATCH * NH * SEQ * DK * 2);
    bf16* kpk   = (bf16*)carve((size_t)BATCH * NH * SEQ * DK * 2);
    bf16* vpk   = (bf16*)carve((size_t)BATCH * NH * SEQ * DK * 2);
    bf16* ao    = (bf16*)carve((size_t)NTOK * D_MODEL * 2);
    float2* tab = (float2*)carve((size_t)SEQ * 32 * sizeof(float2));

    k_tab<<<256, 256, 0, stream>>>(tab);
    k_rmsnorm<<<NTOK, 256, 0, stream>>>(h, g, hn);
    k_packT3<<<dim3(32, 96), dim3(32, 8), 0, stream>>>(wq, wk, wv, wqkvT);
    k_packT1<<<dim3(32, 32), dim3(32, 8), 0, stream>>>(wo, woT);
    k_gemm128_qkv<<<dim3(24, 32), 256, 0, stream>>>(hn, wqkvT, bq, bk, bv, qb, kpk, vpk);
    k_rope_q<<<1024, 256, 0, stream>>>(qb, tab);
    k_rope_kp<<<512, 256, 0, stream>>>(kpk, tab);
    k_attn4<<<512, 256, 0, stream>>>(qb, kpk, vpk, ao);
    k_gemm128_out<<<dim3(8, 32), 256, 0, stream>>>(ao, woT, bo, h, out);
}

// Round 6
// 138.330 us; speedup vs baseline: 2.0858x; 1.1108x over previous
//
#include <hip/hip_runtime.h>
#include <hip/hip_bf16.h>

#define D_MODEL 1024
#define NH 16
#define DK 64
#define SEQ 2048
#define BATCH 2
#define NTOK (BATCH * SEQ)   // 4096
#define EPS 1e-6f

typedef __attribute__((ext_vector_type(4))) float f32x4;
typedef __attribute__((ext_vector_type(16))) float f32x16;
typedef __attribute__((ext_vector_type(8))) short s16x8;
typedef unsigned int u32;
typedef __hip_bfloat16 bf16;

#define AS1 __attribute__((address_space(1)))
#define AS3 __attribute__((address_space(3)))

static __device__ __forceinline__ s16x8 ld8(const bf16* p) {
    return *reinterpret_cast<const s16x8*>(p);
}
// bf16 bits (in a short) -> float, no address-of
static __device__ __forceinline__ float b2f(short s) {
    return __uint_as_float(((u32)(unsigned short)s) << 16);
}

static __device__ __forceinline__ u32 cvtpk(float lo, float hi) {
    u32 r;
    asm volatile("v_cvt_pk_bf16_f32 %0, %1, %2" : "=v"(r) : "v"(lo), "v"(hi));
    return r;
}
static __device__ __forceinline__ void swap32(u32& a, u32& b) {
    asm volatile("v_permlane32_swap_b32 %0, %1" : "+v"(a), "+v"(b));
}
// hardware exp2 (v_exp_f32 computes 2^x)
static __device__ __forceinline__ float exp2f_fast(float x) {
    float r;
    asm("v_exp_f32 %0, %1" : "=v"(r) : "v"(x));
    return r;
}
// async global->LDS, 16B per lane; lds dest must be wave-uniform base (HW adds lane*16)
static __device__ __forceinline__ void gld_lds16(const bf16* g, bf16* l) {
    __builtin_amdgcn_global_load_lds((const AS1 void*)g, (AS3 void*)l, 16, 0, 0);
}

union W4 { s16x8 v; u32 w[4]; };

// swizzled LDS tile read: tile[row][ (kc ^ (row&7)) * 8 ] as 16B
// (write side pre-swizzles the GLOBAL source column so LDS dest stays linear — rule 21)
#define LDSW(arr, row, kc) ld8(&arr[(row)][(((kc) ^ ((row) & 7)) << 3)])

// ---------------- cos/sin table: tab[s][i] for s<2048, i<32 ----------------
__global__ __launch_bounds__(256) void k_tab(float2* __restrict__ tab) {
    const int idx = blockIdx.x * 256 + threadIdx.x;   // 65536
    const int s = idx >> 5, i = idx & 31;
    const float theta = __expf(-(float)i * 0.28782313662425572f);  // ln(10000)/32
    float sn, cs;
    sincosf((float)s * theta, &sn, &cs);
    tab[idx] = make_float2(cs, sn);
}

// ---------------- RMSNorm: h[4096][1024] fp32 -> hn bf16 ----------------
__global__ __launch_bounds__(256) void k_rmsnorm(const float* __restrict__ h,
                                                 const float* __restrict__ g,
                                                 bf16* __restrict__ hn) {
    const int row = blockIdx.x;
    const int tid = threadIdx.x;
    const float4 x = reinterpret_cast<const float4*>(h + (size_t)row * D_MODEL)[tid];
    float ss = x.x * x.x + x.y * x.y + x.z * x.z + x.w * x.w;
#pragma unroll
    for (int off = 32; off; off >>= 1) ss += __shfl_xor(ss, off);
    __shared__ float red[4];
    if ((tid & 63) == 0) red[tid >> 6] = ss;
    __syncthreads();
    const float tot = red[0] + red[1] + red[2] + red[3];
    const float rs = rsqrtf(tot * (1.0f / D_MODEL) + EPS);
    const float4 gg = reinterpret_cast<const float4*>(g)[tid];
    bf16* o = hn + (size_t)row * D_MODEL + tid * 4;
    o[0] = __float2bfloat16(x.x * rs * gg.x);
    o[1] = __float2bfloat16(x.y * rs * gg.y);
    o[2] = __float2bfloat16(x.z * rs * gg.z);
    o[3] = __float2bfloat16(x.w * rs * gg.w);
}

// ------------- pack wq|wk|wv fp32 [K][N] -> bf16 dst[3072][1024] (transposed) -------------
__global__ __launch_bounds__(256) void k_packT3(const float* __restrict__ wq,
                                                const float* __restrict__ wk,
                                                const float* __restrict__ wv,
                                                bf16* __restrict__ dst) {
    __shared__ float t[32][33];
    const int kt = blockIdx.x * 32;
    const int nt = blockIdx.y * 32;
    const float* W = (blockIdx.y < 32) ? wq : (blockIdx.y < 64) ? wk : wv;
    const int nl = nt & (D_MODEL - 1);
    const int tx = threadIdx.x, ty = threadIdx.y;
#pragma unroll
    for (int i = 0; i < 4; i++)
        t[ty + 8 * i][tx] = W[(size_t)(kt + ty + 8 * i) * D_MODEL + nl + tx];
    __syncthreads();
#pragma unroll
    for (int i = 0; i < 4; i++)
        dst[(size_t)(nt + ty + 8 * i) * D_MODEL + kt + tx] = __float2bfloat16(t[tx][ty + 8 * i]);
}

__global__ __launch_bounds__(256) void k_packT1(const float* __restrict__ w,
                                                bf16* __restrict__ dst) {
    __shared__ float t[32][33];
    const int kt = blockIdx.x * 32;
    const int nt = blockIdx.y * 32;
    const int tx = threadIdx.x, ty = threadIdx.y;
#pragma unroll
    for (int i = 0; i < 4; i++)
        t[ty + 8 * i][tx] = w[(size_t)(kt + ty + 8 * i) * D_MODEL + nt + tx];
    __syncthreads();
#pragma unroll
    for (int i = 0; i < 4; i++)
        dst[(size_t)(nt + ty + 8 * i) * D_MODEL + kt + tx] = __float2bfloat16(t[tx][ty + 8 * i]);
}

// ------------- QKV GEMM 128x128 tile, BK=64, swizzled LDS, fused RoPE epilogue -------------
// A: hn[4096][1024], Bt: wqkvT[3072][1024]. Outputs:
//   Q -> qb row-major [bh][s][64]  (RoPE'd + pre-scaled 0.125*log2e)
//   K -> kpk packed   [bh][jb=s/32][t=d/16][lane=(d>>3&1)*32 + s&31][e=d&7]  (RoPE'd)
//   V -> vpk packed   [bh][tile=s/64][dblk=d/32][m=(s>>4)&3][lane=((s>>3)&1)*32 + d&31][e=s&7]
__global__ __launch_bounds__(256) void k_gemm128_qkv(const bf16* __restrict__ A,
                                                     const bf16* __restrict__ Bt,
                                                     const float* __restrict__ bq,
                                                     const float* __restrict__ bk,
                                                     const float* __restrict__ bv,
                                                     const float2* __restrict__ tab,
                                                     bf16* __restrict__ qb,
                                                     bf16* __restrict__ kpk,
                                                     bf16* __restrict__ vpk) {
    __shared__ __align__(16) char smem[32768];
    bf16(*As)[64] = (bf16(*)[64])smem;
    bf16(*Bs)[64] = (bf16(*)[64])(smem + 16384);
    const int tid = threadIdx.x;
    const int w = tid >> 6, lane = tid & 63, l16 = lane & 15, lq = lane >> 4;
    const int wr = w >> 1, wc = w & 1;
    const int row0 = blockIdx.y * 128, col0 = blockIdx.x * 128;
    const int grow = lane >> 3;
    const int scol = (((lane & 7) ^ grow) << 3);     // pre-swizzled source column
    f32x4 acc[4][4];
#pragma unroll
    for (int i = 0; i < 4; i++)
#pragma unroll
        for (int j = 0; j < 4; j++) acc[i][j] = f32x4{0, 0, 0, 0};

    for (int kt = 0; kt < D_MODEL; kt += 64) {
#pragma unroll
        for (int j = 0; j < 4; j++)
            gld_lds16(A + (size_t)(row0 + (w * 4 + j) * 8 + grow) * D_MODEL + kt + scol,
                      &As[(w * 4 + j) * 8][0]);
#pragma unroll
        for (int j = 0; j < 4; j++)
            gld_lds16(Bt + (size_t)(col0 + (w * 4 + j) * 8 + grow) * D_MODEL + kt + scol,
                      &Bs[(w * 4 + j) * 8][0]);
        __syncthreads();
#pragma unroll
        for (int ks = 0; ks < 2; ks++) {
            s16x8 af[4], bfr[4];
#pragma unroll
            for (int mi = 0; mi < 4; mi++) af[mi] = LDSW(As, wr * 64 + mi * 16 + l16, ks * 4 + lq);
#pragma unroll
            for (int ni = 0; ni < 4; ni++) bfr[ni] = LDSW(Bs, wc * 64 + ni * 16 + l16, ks * 4 + lq);
#pragma unroll
            for (int mi = 0; mi < 4; mi++)
#pragma unroll
                for (int ni = 0; ni < 4; ni++)
                    acc[mi][ni] = __builtin_amdgcn_mfma_f32_16x16x32_bf16(af[mi], bfr[ni], acc[mi][ni], 0, 0, 0);
        }
        __syncthreads();
    }

    const int sect = col0 >> 10;
    const int b_ = row0 >> 11;
    if (sect == 2) {
        // V: direct packed stores, 8B each
        const int hi_s = (lq >> 1) & 1, e0 = (lq & 1) * 4;
#pragma unroll
        for (int ni = 0; ni < 4; ni++) {
            const int dglob = col0 + wc * 64 + ni * 16 + l16;
            const int head = (dglob >> 6) & (NH - 1);
            const int dd = dglob & 63;
            const float bs = bv[dglob & 1023];
            bf16* dstH = vpk + ((size_t)(b_ * NH + head) << 17);
#pragma unroll
            for (int mi = 0; mi < 4; mi++) {
                const int tileL = ((row0 & (SEQ - 1)) >> 6) + wr;
                size_t off = ((((size_t)(tileL * 2 + (dd >> 5)) * 4 + mi) * 64 + hi_s * 32 + (dd & 31)) << 3) + e0;
                uint2 pv;
                pv.x = cvtpk(acc[mi][ni][0] + bs, acc[mi][ni][1] + bs);
                pv.y = cvtpk(acc[mi][ni][2] + bs, acc[mi][ni][3] + bs);
                *reinterpret_cast<uint2*>(dstH + off) = pv;
            }
        }
        return;
    }
    // Q / K: restage through swizzled Cs, then fused RoPE + vector/packed stores
    const float* bias = (sect == 0) ? bq : bk;
#pragma unroll
    for (int ni = 0; ni < 4; ni++) {
        const int cl = wc * 64 + ni * 16 + l16;
        const float bs = bias[(col0 & 1023) + cl];
#pragma unroll
        for (int mi = 0; mi < 4; mi++) {
            const int rl = wr * 64 + mi * 16 + lq * 4;
#pragma unroll
            for (int r = 0; r < 4; r++) {
                const int rr = rl + r;
                *(bf16*)(smem + (((rr * 256) + cl * 2) ^ ((rr & 15) << 4))) =
                    __float2bfloat16(acc[mi][ni][r] + bs);
            }
        }
    }
    __syncthreads();
    const int row = tid >> 1, ch = tid & 1;
    const int s_ = (row0 + row) & (SEQ - 1);
    const int head = ((col0 + ch * 64) & 1023) >> 6;
    const float2* tb = tab + s_ * 32;
    const float qs = (sect == 0) ? 0.18033688011112042f : 1.0f;   // 0.125*log2(e) for Q
    bf16* qdst = qb + (((size_t)(b_ * NH + head) * SEQ + s_) << 6);
    bf16* kdst = kpk + ((size_t)(b_ * NH + head) << 17);
    const int jb = s_ >> 5, j31 = s_ & 31;
#pragma unroll
    for (int c = 0; c < 4; c++) {
        const int clo = ch * 8 + c, chi = clo + 4;
        const s16x8 vlo = ld8((const bf16*)(smem + row * 256 + ((clo ^ (row & 15)) << 4)));
        const s16x8 vhi = ld8((const bf16*)(smem + row * 256 + ((chi ^ (row & 15)) << 4)));
        u32 plo[4], phi[4];
#pragma unroll
        for (int e2 = 0; e2 < 4; e2++) {
            float a[2], b[2];
#pragma unroll
            for (int k = 0; k < 2; k++) {
                const int e = e2 * 2 + k;
                const float2 cs = tb[c * 8 + e];
                const float x1 = b2f(vlo[e]), x2 = b2f(vhi[e]);
                a[k] = (x1 * cs.x - x2 * cs.y) * qs;
                b[k] = (x2 * cs.x + x1 * cs.y) * qs;
            }
            plo[e2] = cvtpk(a[0], a[1]);
            phi[e2] = cvtpk(b[0], b[1]);
        }
        if (sect == 0) {
            *reinterpret_cast<uint4*>(qdst + c * 8)        = make_uint4(plo[0], plo[1], plo[2], plo[3]);
            *reinterpret_cast<uint4*>(qdst + 32 + c * 8)   = make_uint4(phi[0], phi[1], phi[2], phi[3]);
        } else {
            // chunk c -> (t=c>>1, hi=c&1); chunk c+4 likewise
            const size_t offL = (((size_t)(jb * 4 + (c >> 1)) * 64 + (c & 1) * 32 + j31) << 3);
            const size_t offH = (((size_t)(jb * 4 + ((c + 4) >> 1)) * 64 + ((c + 4) & 1) * 32 + j31) << 3);
            *reinterpret_cast<uint4*>(kdst + offL) = make_uint4(plo[0], plo[1], plo[2], plo[3]);
            *reinterpret_cast<uint4*>(kdst + offH) = make_uint4(phi[0], phi[1], phi[2], phi[3]);
        }
    }
}

// ------------- causal flash attention: pipelined, XCD-local, exp2 softmax -------------
__global__ __launch_bounds__(256) void k_attn4(const bf16* __restrict__ qg,
                                               const bf16* __restrict__ kp,
                                               const bf16* __restrict__ vp,
                                               bf16* __restrict__ ao) {
    const int tid = threadIdx.x;
    const int w = tid >> 6;
    const int lane = tid & 63;
    const int l31 = lane & 31;
    const int hi = lane >> 5;
    const int bid = blockIdx.x;          // 0..511
    const int blk = (bid >> 3) & 15;
    const int bh  = (bid & 7) + ((bid >> 7) << 3);
    int pos;
    switch (w) {
        case 0:  pos = blk;      break;
        case 1:  pos = 31 - blk; break;
        case 2:  pos = 32 + blk; break;
        default: pos = 63 - blk; break;
    }
    const int qw = pos << 5;
    const int qrow = qw + l31;

    const bf16* qptr = qg + (((size_t)bh * SEQ + qrow) << 6) + 8 * hi;
    s16x8 qf[4];
#pragma unroll
    for (int t = 0; t < 4; t++) qf[t] = ld8(qptr + 16 * t);

    f32x16 o0, o1;
#pragma unroll
    for (int r = 0; r < 16; r++) { o0[r] = 0.0f; o1[r] = 0.0f; }
    float m_run = -1e30f, l_run = 0.0f;

    const int nfull = qw >> 6;
    const int ntot  = (qw + 95) >> 6;
    const bf16* kbase = kp + ((size_t)bh << 17);
    const bf16* vbase = vp + ((size_t)bh << 17);

    s16x8 kA[8], kB[8], vC[8];
#pragma unroll
    for (int t = 0; t < 8; t++) kA[t] = ld8(kbase + (((size_t)t * 64 + lane) << 3));

    auto att_step = [&](s16x8(&KC)[8], s16x8(&KN)[8], const int kt) {
        const int kb = kt << 6;
#pragma unroll
        for (int t = 0; t < 8; t++)
            vC[t] = ld8(vbase + (((size_t)(kt * 8 + t) * 64 + lane) << 3));
        f32x16 s0, s1;
#pragma unroll
        for (int r = 0; r < 16; r++) { s0[r] = 0.0f; s1[r] = 0.0f; }
        __builtin_amdgcn_s_setprio(1);
#pragma unroll
        for (int t = 0; t < 4; t++) {
            s0 = __builtin_amdgcn_mfma_f32_32x32x16_bf16(KC[t],     qf[t], s0, 0, 0, 0);
            s1 = __builtin_amdgcn_mfma_f32_32x32x16_bf16(KC[4 + t], qf[t], s1, 0, 0, 0);
        }
        __builtin_amdgcn_s_setprio(0);
        const int ktn = (kt + 1 < ntot) ? kt + 1 : kt;
#pragma unroll
        for (int t = 0; t < 8; t++)
            KN[t] = ld8(kbase + (((size_t)(ktn * 8 + t) * 64 + lane) << 3));
        float p[32];
#pragma unroll
        for (int r = 0; r < 16; r++) { p[r] = s0[r]; p[16 + r] = s1[r]; }
        if (kt >= nfull) {
#pragma unroll
            for (int r = 0; r < 32; r++) {
                const int j = kb + 8 * (r >> 2) + (r & 3) + 4 * hi;
                if (j > qrow) p[r] = -3.0e38f;
            }
        }
        float m16[16];
#pragma unroll
        for (int r = 0; r < 16; r++) m16[r] = fmaxf(p[r], p[r + 16]);
#pragma unroll
        for (int r = 0; r < 8; r++) m16[r] = fmaxf(m16[r], m16[r + 8]);
#pragma unroll
        for (int r = 0; r < 4; r++) m16[r] = fmaxf(m16[r], m16[r + 4]);
        float mx = fmaxf(fmaxf(m16[0], m16[1]), fmaxf(m16[2], m16[3]));
        mx = fmaxf(mx, __shfl_xor(mx, 32));
        if (!__all(mx <= m_run + 8.0f)) {   // defer-max (T13), exp2-domain
            const float mn = fmaxf(m_run, mx);
            const float alpha = exp2f_fast(m_run - mn);
            m_run = mn;
            l_run *= alpha;
#pragma unroll
            for (int r = 0; r < 16; r++) { o0[r] *= alpha; o1[r] *= alpha; }
        }
        float s4[4] = {0, 0, 0, 0};
#pragma unroll
        for (int r = 0; r < 32; r++) { p[r] = exp2f_fast(p[r] - m_run); s4[r & 3] += p[r]; }
        float rs = (s4[0] + s4[1]) + (s4[2] + s4[3]);
        rs += __shfl_xor(rs, 32);
        l_run += rs;
        u32 pk_[16];
#pragma unroll
        for (int a = 0; a < 8; a++) {
            pk_[2 * a]     = cvtpk(p[4 * a],     p[4 * a + 1]);
            pk_[2 * a + 1] = cvtpk(p[4 * a + 2], p[4 * a + 3]);
        }
        __builtin_amdgcn_s_setprio(1);
#pragma unroll
        for (int m = 0; m < 4; m++) {
            u32 b0 = pk_[4 * m],     b2 = pk_[4 * m + 2];
            u32 b1 = pk_[4 * m + 1], b3 = pk_[4 * m + 3];
            swap32(b0, b2);
            swap32(b1, b3);
            W4 B; B.w[0] = b0; B.w[1] = b1; B.w[2] = b2; B.w[3] = b3;
            o0 = __builtin_amdgcn_mfma_f32_32x32x16_bf16(vC[m],     B.v, o0, 0, 0, 0);
            o1 = __builtin_amdgcn_mfma_f32_32x32x16_bf16(vC[4 + m], B.v, o1, 0, 0, 0);
        }
        __builtin_amdgcn_s_setprio(0);
    };

    int kt = 0;
    for (;;) {
        att_step(kA, kB, kt); if (++kt == ntot) break;
        att_step(kB, kA, kt); if (++kt == ntot) break;
    }

    const float inv = 1.0f / l_run;
    const int b_ = bh >> 4, h_ = bh & (NH - 1);
    bf16* orow = ao + (((size_t)(b_ * SEQ + qrow)) << 10) + (h_ << 6);
#pragma unroll
    for (int g = 0; g < 4; g++) {
        {
            uint2 val;
            val.x = cvtpk(o0[4 * g] * inv, o0[4 * g + 1] * inv);
            val.y = cvtpk(o0[4 * g + 2] * inv, o0[4 * g + 3] * inv);
            *reinterpret_cast<uint2*>(orow + 8 * g + 4 * hi) = val;
        }
        {
            uint2 val;
            val.x = cvtpk(o1[4 * g] * inv, o1[4 * g + 1] * inv);
            val.y = cvtpk(o1[4 * g + 2] * inv, o1[4 * g + 3] * inv);
            *reinterpret_cast<uint2*>(orow + 32 + 8 * g + 4 * hi) = val;
        }
    }
}

// ------------- O-proj GEMM 128x128 (swizzled LDS) + bias + residual -> fp32 out -------------
__global__ __launch_bounds__(256) void k_gemm128_out(const bf16* __restrict__ A,
                                                     const bf16* __restrict__ Bt,
                                                     const float* __restrict__ bo,
                                                     const float* __restrict__ hres,
                                                     float* __restrict__ out) {
    __shared__ __align__(16) char smem[32768];
    bf16(*As)[64] = (bf16(*)[64])smem;
    bf16(*Bs)[64] = (bf16(*)[64])(smem + 16384);
    const int tid = threadIdx.x;
    const int w = tid >> 6, lane = tid & 63, l16 = lane & 15, lq = lane >> 4;
    const int wr = w >> 1, wc = w & 1;
    const int row0 = blockIdx.y * 128, col0 = blockIdx.x * 128;
    const int grow = lane >> 3;
    const int scol = (((lane & 7) ^ grow) << 3);
    f32x4 acc[4][4];
#pragma unroll
    for (int i = 0; i < 4; i++)
#pragma unroll
        for (int j = 0; j < 4; j++) acc[i][j] = f32x4{0, 0, 0, 0};

    for (int kt = 0; kt < D_MODEL; kt += 64) {
#pragma unroll
        for (int j = 0; j < 4; j++)
            gld_lds16(A + (size_t)(row0 + (w * 4 + j) * 8 + grow) * D_MODEL + kt + scol,
                      &As[(w * 4 + j) * 8][0]);
#pragma unroll
        for (int j = 0; j < 4; j++)
            gld_lds16(Bt + (size_t)(col0 + (w * 4 + j) * 8 + grow) * D_MODEL + kt + scol,
                      &Bs[(w * 4 + j) * 8][0]);
        __syncthreads();
#pragma unroll
        for (int ks = 0; ks < 2; ks++) {
            s16x8 af[4], bfr[4];
#pragma unroll
            for (int mi = 0; mi < 4; mi++) af[mi] = LDSW(As, wr * 64 + mi * 16 + l16, ks * 4 + lq);
#pragma unroll
            for (int ni = 0; ni < 4; ni++) bfr[ni] = LDSW(Bs, wc * 64 + ni * 16 + l16, ks * 4 + lq);
#pragma unroll
            for (int mi = 0; mi < 4; mi++)
#pragma unroll
                for (int ni = 0; ni < 4; ni++)
                    acc[mi][ni] = __builtin_amdgcn_mfma_f32_16x16x32_bf16(af[mi], bfr[ni], acc[mi][ni], 0, 0, 0);
        }
        __syncthreads();
    }
#pragma unroll
    for (int ni = 0; ni < 4; ni++) {
        const int col = col0 + wc * 64 + ni * 16 + l16;
        const float bs = bo[col];
#pragma unroll
        for (int mi = 0; mi < 4; mi++) {
#pragma unroll
            for (int r = 0; r < 4; r++) {
                const int row = row0 + wr * 64 + mi * 16 + lq * 4 + r;
                out[(size_t)row * D_MODEL + col] =
                    acc[mi][ni][r] + bs + hres[(size_t)row * D_MODEL + col];
            }
        }
    }
}

extern "C" void kernel_launch(void* const* d_in, const int* in_sizes, int n_in,
                              void* d_out, int out_size, void* d_ws, size_t ws_size,
                              hipStream_t stream) {
    (void)in_sizes; (void)n_in; (void)out_size; (void)ws_size;
    const float* h  = (const float*)d_in[0];
    const float* wq = (const float*)d_in[1];
    const float* bq = (const float*)d_in[2];
    const float* wk = (const float*)d_in[3];
    const float* bk = (const float*)d_in[4];
    const float* wv = (const float*)d_in[5];
    const float* bv = (const float*)d_in[6];
    const float* wo = (const float*)d_in[7];
    const float* bo = (const float*)d_in[8];
    const float* g  = (const float*)d_in[9];
    float* out = (float*)d_out;

    char* ws = (char*)d_ws;
    size_t off = 0;
    auto carve = [&](size_t bytes) {
        void* p = ws + off;
        off += (bytes + 255) & ~(size_t)255;
        return p;
    };
    bf16* hn    = (bf16*)carve((size_t)NTOK * D_MODEL * 2);
    bf16* wqkvT = (bf16*)carve((size_t)3 * D_MODEL * D_MODEL * 2);
    bf16* woT   = (bf16*)carve((size_t)D_MODEL * D_MODEL * 2);
    bf16* qb    = (bf16*)carve((size_t)BATCH * NH * SEQ * DK * 2);
    bf16* kpk   = (bf16*)carve((size_t)BATCH * NH * SEQ * DK * 2);
    bf16* vpk   = (bf16*)carve((size_t)BATCH * NH * SEQ * DK * 2);
    bf16* ao    = (bf16*)carve((size_t)NTOK * D_MODEL * 2);
    float2* tab = (float2*)carve((size_t)SEQ * 32 * sizeof(float2));

    k_tab<<<256, 256, 0, stream>>>(tab);
    k_rmsnorm<<<NTOK, 256, 0, stream>>>(h, g, hn);
    k_packT3<<<dim3(32, 96), dim3(32, 8), 0, stream>>>(wq, wk, wv, wqkvT);
    k_packT1<<<dim3(32, 32), dim3(32, 8), 0, stream>>>(wo, woT);
    k_gemm128_qkv<<<dim3(24, 32), 256, 0, stream>>>(hn, wqkvT, bq, bk, bv, tab, qb, kpk, vpk);
    k_attn4<<<512, 256, 0, stream>>>(qb, kpk, vpk, ao);
    k_gemm128_out<<<dim3(8, 32), 256, 0, stream>>>(ao, woT, bo, h, out);
}